// Round 1
// baseline (662.288 us; speedup 1.0000x reference)
//
#include <hip/hip_runtime.h>
#include <hip/hip_bf16.h>
#include <stdint.h>

// ---------------------------------------------------------------------------
// GPT-2 block on MI355X (gfx950). Round 0: correctness-first full pipeline.
// bf16 MFMA (16x16x32) GEMMs in the m97-proven 128x128-tile structure,
// causal flash attention with online softmax, fused epilogues.
// ---------------------------------------------------------------------------

typedef short bf16x8 __attribute__((ext_vector_type(8)));
typedef float f32x4  __attribute__((ext_vector_type(4)));
typedef short s16x4  __attribute__((ext_vector_type(4)));

__device__ __forceinline__ short f2bf(float f) {
  union { float f; uint32_t u; } a;
  a.f = f;
  uint32_t r = a.u + 0x7fffu + ((a.u >> 16) & 1u);  // RNE
  return (short)(r >> 16);
}

__device__ __forceinline__ void gload_lds16(const void* g, void* l) {
  __builtin_amdgcn_global_load_lds(
      (const __attribute__((address_space(1))) void*)g,
      (__attribute__((address_space(3))) void*)l, 16, 0, 0);
}

__device__ __forceinline__ float gelu_f(float x) {
  float y = 0.7978845608028654f * (x + 0.044715f * x * x * x);
  y = fminf(fmaxf(y, -20.f), 20.f);
  float e = __expf(2.f * y);
  return 0.5f * x * (1.f + (e - 1.f) / (e + 1.f));  // tanh via exp
}

// --------------------------- weight fp32 -> bf16 ---------------------------
__global__ __launch_bounds__(256)
void cvt_f32_bf16(const float* __restrict__ in, short* __restrict__ out, int n4) {
  int i = blockIdx.x * 256 + threadIdx.x;
  if (i < n4) {
    float4 v = ((const float4*)in)[i];
    s16x4 o;
    o[0] = f2bf(v.x); o[1] = f2bf(v.y); o[2] = f2bf(v.z); o[3] = f2bf(v.w);
    ((s16x4*)out)[i] = o;
  }
}

// ------------------------------- LayerNorm ---------------------------------
// One block per row, D=1024, 256 threads * 1 float4 each. Output bf16.
__global__ __launch_bounds__(256)
void ln_fwd(const float* __restrict__ x, const float* __restrict__ g,
            const float* __restrict__ b, short* __restrict__ y) {
  const long row = blockIdx.x;
  const int t = threadIdx.x;
  const float4 xv = ((const float4*)(x + row * 1024))[t];
  float s  = xv.x + xv.y + xv.z + xv.w;
  float ss = xv.x * xv.x + xv.y * xv.y + xv.z * xv.z + xv.w * xv.w;
#pragma unroll
  for (int m = 1; m < 64; m <<= 1) {
    s  += __shfl_xor(s, m);
    ss += __shfl_xor(ss, m);
  }
  __shared__ float rs[4], rss[4];
  const int wid = t >> 6, lane = t & 63;
  if (lane == 0) { rs[wid] = s; rss[wid] = ss; }
  __syncthreads();
  s  = rs[0] + rs[1] + rs[2] + rs[3];
  ss = rss[0] + rss[1] + rss[2] + rss[3];
  const float mu   = s * (1.f / 1024.f);
  const float var  = ss * (1.f / 1024.f) - mu * mu;
  const float rstd = rsqrtf(var + 1e-5f);
  const float4 gv = ((const float4*)g)[t];
  const float4 bv = ((const float4*)b)[t];
  s16x4 ov;
  ov[0] = f2bf((xv.x - mu) * rstd * gv.x + bv.x);
  ov[1] = f2bf((xv.y - mu) * rstd * gv.y + bv.y);
  ov[2] = f2bf((xv.z - mu) * rstd * gv.z + bv.z);
  ov[3] = f2bf((xv.w - mu) * rstd * gv.w + bv.w);
  *(s16x4*)(y + row * 1024 + t * 4) = ov;
}

// ------------------------------- GEMM (NT) ----------------------------------
// C[M,N] = A[M,K](bf16) . W[N,K](bf16)^T + bias (+res) (+gelu)
// 128x128 tile, BK=64, 4 waves (each 64x64 = 4x4 MFMA frags), m97 structure:
// global_load_lds width-16 staging into linear LDS, 2 barriers per K-step.
template <int OUT_BF16, int HAS_RES, int HAS_GELU>
__global__ __launch_bounds__(256, 2)
void gemm_bt(const short* __restrict__ A, const short* __restrict__ W,
             const float* __restrict__ bias, const float* __restrict__ res,
             void* __restrict__ out, int M, int N, int K) {
  __shared__ short As[128 * 64];
  __shared__ short Bs[128 * 64];
  const int tid = threadIdx.x;
  const int wid = tid >> 6, lane = tid & 63;
  const int l16 = lane & 15, lg = lane >> 4;
  const int brow = blockIdx.y * 128, bcol = blockIdx.x * 128;
  const int wr = (wid >> 1) * 64, wc = (wid & 1) * 64;

  f32x4 acc[4][4] = {};

  const int r0 = tid >> 3;            // staging row (chunk c = i*256+tid, row = i*32 + r0)
  const int e8 = (tid & 7) * 8;       // staging k-offset (elements)
  const short* ga = A + (long)(brow + r0) * K + e8;
  const short* gb = W + (long)(bcol + r0) * K + e8;

  for (int kt = 0; kt < K; kt += 64) {
    __syncthreads();
#pragma unroll
    for (int i = 0; i < 4; ++i) {
      gload_lds16(ga + (long)i * 32 * K + kt, &As[(i * 256 + wid * 64) * 8]);
      gload_lds16(gb + (long)i * 32 * K + kt, &Bs[(i * 256 + wid * 64) * 8]);
    }
    __syncthreads();
#pragma unroll
    for (int kk = 0; kk < 2; ++kk) {
      const int ko = kk * 32 + lg * 8;
      bf16x8 af[4], bf[4];
#pragma unroll
      for (int m = 0; m < 4; ++m)
        af[m] = *(const bf16x8*)&As[(wr + m * 16 + l16) * 64 + ko];
#pragma unroll
      for (int n = 0; n < 4; ++n)
        bf[n] = *(const bf16x8*)&Bs[(wc + n * 16 + l16) * 64 + ko];
#pragma unroll
      for (int m = 0; m < 4; ++m)
#pragma unroll
        for (int n = 0; n < 4; ++n)
          acc[m][n] = __builtin_amdgcn_mfma_f32_16x16x32_bf16(af[m], bf[n], acc[m][n], 0, 0, 0);
    }
  }

  // epilogue: C/D layout col = lane&15, row = (lane>>4)*4 + j  [m89-verified]
#pragma unroll
  for (int n = 0; n < 4; ++n) {
    const int col = bcol + wc + n * 16 + l16;
    const float bb = bias[col];
#pragma unroll
    for (int m = 0; m < 4; ++m) {
#pragma unroll
      for (int j = 0; j < 4; ++j) {
        const long row = brow + wr + m * 16 + lg * 4 + j;
        float vv = acc[m][n][j] + bb;
        if (HAS_GELU) vv = gelu_f(vv);
        if (HAS_RES) vv += res[row * N + col];
        if (OUT_BF16) ((short*)out)[row * N + col] = f2bf(vv);
        else          ((float*)out)[row * N + col] = vv;
      }
    }
  }
}

// --------------------------- causal flash attention -------------------------
// q,k,v,o: bf16 [B*S, D] with head h at cols [h*64, h*64+64).
// Block: 128 q-rows of one (b,h); 4 waves x 32 rows. K/V tiles of 64 keys.
__global__ __launch_bounds__(256, 2)
void attn_fwd(const short* __restrict__ q, const short* __restrict__ k,
              const short* __restrict__ v, short* __restrict__ o,
              int S, int D, int H) {
  const int tid = threadIdx.x, wid = tid >> 6, lane = tid & 63;
  const int l16 = lane & 15, lg = lane >> 4;
  const int h = blockIdx.y % H, bidx = blockIdx.y / H;
  const int q0 = blockIdx.x * 128;
  const long base = (long)bidx * S * D + h * 64;

  __shared__ short Ks[64 * 64];
  __shared__ short Vt[64 * 64];       // transposed: Vt[dh][key]
  __shared__ short Ps[4][32 * 64];    // per-wave P tile

  const int qw = q0 + wid * 32;

  bf16x8 qf[2][2];
#pragma unroll
  for (int m = 0; m < 2; ++m)
#pragma unroll
    for (int kk = 0; kk < 2; ++kk)
      qf[m][kk] = *(const bf16x8*)&q[base + (long)(qw + m * 16 + l16) * D + kk * 32 + lg * 8];

  f32x4 oa[2][4] = {};
  float mr[2][4], lr[2][4];
#pragma unroll
  for (int m = 0; m < 2; ++m)
#pragma unroll
    for (int j = 0; j < 4; ++j) { mr[m][j] = -1e30f; lr[m][j] = 0.f; }

  const int ntiles = q0 / 64 + 2;
  for (int t = 0; t < ntiles; ++t) {
    const int k0 = t * 64;
    __syncthreads();
    // stage K [64 keys][64 dh] via global_load_lds (linear layout)
#pragma unroll
    for (int i = 0; i < 2; ++i) {
      const int c = i * 256 + tid;
      const int row = c >> 3, d8 = (c & 7) * 8;
      gload_lds16(&k[base + (long)(k0 + row) * D + d8], &Ks[(i * 256 + wid * 64) * 8]);
    }
    // stage V transposed (coalesced read, scattered LDS write)
#pragma unroll
    for (int i = 0; i < 2; ++i) {
      const int c = i * 256 + tid;
      const int row = c >> 3, d8 = (c & 7) * 8;
      bf16x8 vv = *(const bf16x8*)&v[base + (long)(k0 + row) * D + d8];
#pragma unroll
      for (int j = 0; j < 8; ++j) Vt[(d8 + j) * 64 + row] = vv[j];
    }
    __syncthreads();

    // S = Q K^T (scaled later)
    f32x4 sf[2][4] = {};
#pragma unroll
    for (int kk = 0; kk < 2; ++kk) {
      const int ko = kk * 32 + lg * 8;
      bf16x8 kf[4];
#pragma unroll
      for (int n = 0; n < 4; ++n) kf[n] = *(const bf16x8*)&Ks[(n * 16 + l16) * 64 + ko];
#pragma unroll
      for (int m = 0; m < 2; ++m)
#pragma unroll
        for (int n = 0; n < 4; ++n)
          sf[m][n] = __builtin_amdgcn_mfma_f32_16x16x32_bf16(qf[m][kk], kf[n], sf[m][n], 0, 0, 0);
    }

    const bool need_mask = (k0 + 64 > qw);
#pragma unroll
    for (int m = 0; m < 2; ++m) {
#pragma unroll
      for (int j = 0; j < 4; ++j) {
        const int qi = qw + m * 16 + lg * 4 + j;
        float rm = -1e30f;
#pragma unroll
        for (int n = 0; n < 4; ++n) {
          float val = sf[m][n][j] * 0.125f;
          if (need_mask) {
            const int key = k0 + n * 16 + l16;
            if (key > qi) val = -1e30f;
          }
          sf[m][n][j] = val;
          rm = fmaxf(rm, val);
        }
        rm = fmaxf(rm, __shfl_xor(rm, 1));
        rm = fmaxf(rm, __shfl_xor(rm, 2));
        rm = fmaxf(rm, __shfl_xor(rm, 4));
        rm = fmaxf(rm, __shfl_xor(rm, 8));
        const float mn = fmaxf(mr[m][j], rm);
        const float alpha = __expf(mr[m][j] - mn);
        mr[m][j] = mn;
        lr[m][j] *= alpha;
        float ps = 0.f;
#pragma unroll
        for (int n = 0; n < 4; ++n) {
          const float p = __expf(sf[m][n][j] - mn);
          ps += p;
          Ps[wid][(m * 16 + lg * 4 + j) * 64 + n * 16 + l16] = f2bf(p);
        }
        ps += __shfl_xor(ps, 1);
        ps += __shfl_xor(ps, 2);
        ps += __shfl_xor(ps, 4);
        ps += __shfl_xor(ps, 8);
        lr[m][j] += ps;
#pragma unroll
        for (int n = 0; n < 4; ++n) oa[m][n][j] *= alpha;
      }
    }

    // O += P V   (P re-fragmented through per-wave LDS; wave-local, no barrier)
#pragma unroll
    for (int kk = 0; kk < 2; ++kk) {
      const int ko = kk * 32 + lg * 8;
      bf16x8 pf[2], vf[4];
#pragma unroll
      for (int m = 0; m < 2; ++m) pf[m] = *(const bf16x8*)&Ps[wid][(m * 16 + l16) * 64 + ko];
#pragma unroll
      for (int n = 0; n < 4; ++n) vf[n] = *(const bf16x8*)&Vt[(n * 16 + l16) * 64 + ko];
#pragma unroll
      for (int m = 0; m < 2; ++m)
#pragma unroll
        for (int n = 0; n < 4; ++n)
          oa[m][n] = __builtin_amdgcn_mfma_f32_16x16x32_bf16(pf[m], vf[n], oa[m][n], 0, 0, 0);
    }
  }

  // epilogue: O /= l, store bf16
#pragma unroll
  for (int m = 0; m < 2; ++m)
#pragma unroll
    for (int j = 0; j < 4; ++j) {
      const float inv = 1.f / lr[m][j];
      const long row = qw + m * 16 + lg * 4 + j;
#pragma unroll
      for (int n = 0; n < 4; ++n)
        o[base + row * D + n * 16 + l16] = f2bf(oa[m][n][j] * inv);
    }
}

// ------------------------------- launcher -----------------------------------
extern "C" void kernel_launch(void* const* d_in, const int* in_sizes, int n_in,
                              void* d_out, int out_size, void* d_ws, size_t ws_size,
                              hipStream_t stream) {
  (void)in_sizes; (void)n_in; (void)out_size; (void)ws_size;
  const float* h     = (const float*)d_in[0];
  const float* ln1_g = (const float*)d_in[1];
  const float* ln1_b = (const float*)d_in[2];
  const float* wq    = (const float*)d_in[3];
  const float* bq    = (const float*)d_in[4];
  const float* wk    = (const float*)d_in[5];
  const float* bk    = (const float*)d_in[6];
  const float* wv    = (const float*)d_in[7];
  const float* bv    = (const float*)d_in[8];
  const float* wo    = (const float*)d_in[9];
  const float* bo    = (const float*)d_in[10];
  const float* ln2_g = (const float*)d_in[11];
  const float* ln2_b = (const float*)d_in[12];
  const float* wfc   = (const float*)d_in[13];
  const float* bfc   = (const float*)d_in[14];
  const float* wproj = (const float*)d_in[15];
  const float* bproj = (const float*)d_in[16];

  const int B = 4, S = 2048, D = 1024, H = 16, F = 4096, T = B * S;

  char* ws = (char*)d_ws;
  size_t off = 0;
  auto alloc = [&](size_t bytes) {
    void* p = ws + off;
    off += (bytes + 255) & ~(size_t)255;
    return p;
  };
  short* xb  = (short*)alloc((size_t)T * D * 2);   // x1 / x2 (reused)
  short* qb  = (short*)alloc((size_t)T * D * 2);
  short* kb  = (short*)alloc((size_t)T * D * 2);
  short* vb  = (short*)alloc((size_t)T * D * 2);
  short* ob  = (short*)alloc((size_t)T * D * 2);
  float* h2  = (float*)alloc((size_t)T * D * 4);
  short* wqb = (short*)alloc((size_t)D * D * 2);
  short* wkb = (short*)alloc((size_t)D * D * 2);
  short* wvb = (short*)alloc((size_t)D * D * 2);
  short* wob = (short*)alloc((size_t)D * D * 2);
  short* wfcb   = (short*)alloc((size_t)F * D * 2);
  short* wprojb = (short*)alloc((size_t)D * F * 2);
  // u [T,F] bf16 (64MB) aliases q/k/v/o (4x16MB contiguous) - all dead by FC time.
  short* ub = qb;

  // weight converts (bf16 for MFMA)
  cvt_f32_bf16<<<dim3(D * D / 4 / 256), 256, 0, stream>>>(wq, wqb, D * D / 4);
  cvt_f32_bf16<<<dim3(D * D / 4 / 256), 256, 0, stream>>>(wk, wkb, D * D / 4);
  cvt_f32_bf16<<<dim3(D * D / 4 / 256), 256, 0, stream>>>(wv, wvb, D * D / 4);
  cvt_f32_bf16<<<dim3(D * D / 4 / 256), 256, 0, stream>>>(wo, wob, D * D / 4);
  cvt_f32_bf16<<<dim3(F * D / 4 / 256), 256, 0, stream>>>(wfc, wfcb, F * D / 4);
  cvt_f32_bf16<<<dim3(D * F / 4 / 256), 256, 0, stream>>>(wproj, wprojb, D * F / 4);

  // attention sub-block
  ln_fwd<<<dim3(T), 256, 0, stream>>>(h, ln1_g, ln1_b, xb);
  gemm_bt<1, 0, 0><<<dim3(D / 128, T / 128), 256, 0, stream>>>(xb, wqb, bq, nullptr, qb, T, D, D);
  gemm_bt<1, 0, 0><<<dim3(D / 128, T / 128), 256, 0, stream>>>(xb, wkb, bk, nullptr, kb, T, D, D);
  gemm_bt<1, 0, 0><<<dim3(D / 128, T / 128), 256, 0, stream>>>(xb, wvb, bv, nullptr, vb, T, D, D);
  attn_fwd<<<dim3(S / 128, B * H), 256, 0, stream>>>(qb, kb, vb, ob, S, D, H);
  gemm_bt<0, 1, 0><<<dim3(D / 128, T / 128), 256, 0, stream>>>(ob, wob, bo, h, h2, T, D, D);

  // MLP sub-block
  ln_fwd<<<dim3(T), 256, 0, stream>>>(h2, ln2_g, ln2_b, xb);
  gemm_bt<1, 0, 1><<<dim3(F / 128, T / 128), 256, 0, stream>>>(xb, wfcb, bfc, nullptr, ub, T, F, D);
  gemm_bt<0, 1, 0><<<dim3(D / 128, T / 128), 256, 0, stream>>>(ub, wprojb, bproj, h2, (float*)d_out, T, D, F);
}

// Round 2
// 593.552 us; speedup vs baseline: 1.1158x; 1.1158x over previous
//
#include <hip/hip_runtime.h>
#include <hip/hip_bf16.h>
#include <stdint.h>

// ---------------------------------------------------------------------------
// GPT-2 block on MI355X (gfx950). Round 2: attention LDS XOR-swizzle (T2).
// All three attn LDS structures (Ks, Vt, Ps) had 128B-stride bank conflicts
// (16-way reads). Ks swizzle is applied via pre-swizzled global source
// (global_load_lds writes linearly); Vt/Ps swizzle on both write and read.
// Long causal blocks dispatch first (reversed q0 mapping).
// ---------------------------------------------------------------------------

typedef short bf16x8 __attribute__((ext_vector_type(8)));
typedef float f32x4  __attribute__((ext_vector_type(4)));
typedef short s16x4  __attribute__((ext_vector_type(4)));

__device__ __forceinline__ short f2bf(float f) {
  union { float f; uint32_t u; } a;
  a.f = f;
  uint32_t r = a.u + 0x7fffu + ((a.u >> 16) & 1u);  // RNE
  return (short)(r >> 16);
}

__device__ __forceinline__ void gload_lds16(const void* g, void* l) {
  __builtin_amdgcn_global_load_lds(
      (const __attribute__((address_space(1))) void*)g,
      (__attribute__((address_space(3))) void*)l, 16, 0, 0);
}

__device__ __forceinline__ float gelu_f(float x) {
  float y = 0.7978845608028654f * (x + 0.044715f * x * x * x);
  y = fminf(fmaxf(y, -20.f), 20.f);
  float e = __expf(2.f * y);
  return 0.5f * x * (1.f + (e - 1.f) / (e + 1.f));  // tanh via exp
}

// --------------------------- weight fp32 -> bf16 ---------------------------
__global__ __launch_bounds__(256)
void cvt_f32_bf16(const float* __restrict__ in, short* __restrict__ out, int n4) {
  int i = blockIdx.x * 256 + threadIdx.x;
  if (i < n4) {
    float4 v = ((const float4*)in)[i];
    s16x4 o;
    o[0] = f2bf(v.x); o[1] = f2bf(v.y); o[2] = f2bf(v.z); o[3] = f2bf(v.w);
    ((s16x4*)out)[i] = o;
  }
}

// ------------------------------- LayerNorm ---------------------------------
__global__ __launch_bounds__(256)
void ln_fwd(const float* __restrict__ x, const float* __restrict__ g,
            const float* __restrict__ b, short* __restrict__ y) {
  const long row = blockIdx.x;
  const int t = threadIdx.x;
  const float4 xv = ((const float4*)(x + row * 1024))[t];
  float s  = xv.x + xv.y + xv.z + xv.w;
  float ss = xv.x * xv.x + xv.y * xv.y + xv.z * xv.z + xv.w * xv.w;
#pragma unroll
  for (int m = 1; m < 64; m <<= 1) {
    s  += __shfl_xor(s, m);
    ss += __shfl_xor(ss, m);
  }
  __shared__ float rs[4], rss[4];
  const int wid = t >> 6, lane = t & 63;
  if (lane == 0) { rs[wid] = s; rss[wid] = ss; }
  __syncthreads();
  s  = rs[0] + rs[1] + rs[2] + rs[3];
  ss = rss[0] + rss[1] + rss[2] + rss[3];
  const float mu   = s * (1.f / 1024.f);
  const float var  = ss * (1.f / 1024.f) - mu * mu;
  const float rstd = rsqrtf(var + 1e-5f);
  const float4 gv = ((const float4*)g)[t];
  const float4 bv = ((const float4*)b)[t];
  s16x4 ov;
  ov[0] = f2bf((xv.x - mu) * rstd * gv.x + bv.x);
  ov[1] = f2bf((xv.y - mu) * rstd * gv.y + bv.y);
  ov[2] = f2bf((xv.z - mu) * rstd * gv.z + bv.z);
  ov[3] = f2bf((xv.w - mu) * rstd * gv.w + bv.w);
  *(s16x4*)(y + row * 1024 + t * 4) = ov;
}

// ------------------------------- GEMM (NT) ----------------------------------
// C[M,N] = A[M,K](bf16) . W[N,K](bf16)^T + bias (+res) (+gelu)
template <int OUT_BF16, int HAS_RES, int HAS_GELU>
__global__ __launch_bounds__(256, 2)
void gemm_bt(const short* __restrict__ A, const short* __restrict__ W,
             const float* __restrict__ bias, const float* __restrict__ res,
             void* __restrict__ out, int M, int N, int K) {
  __shared__ short As[128 * 64];
  __shared__ short Bs[128 * 64];
  const int tid = threadIdx.x;
  const int wid = tid >> 6, lane = tid & 63;
  const int l16 = lane & 15, lg = lane >> 4;
  const int brow = blockIdx.y * 128, bcol = blockIdx.x * 128;
  const int wr = (wid >> 1) * 64, wc = (wid & 1) * 64;

  f32x4 acc[4][4] = {};

  const int r0 = tid >> 3;            // staging row
  const int e8 = (tid & 7) * 8;       // staging k-offset (elements)
  const short* ga = A + (long)(brow + r0) * K + e8;
  const short* gb = W + (long)(bcol + r0) * K + e8;

  for (int kt = 0; kt < K; kt += 64) {
    __syncthreads();
#pragma unroll
    for (int i = 0; i < 4; ++i) {
      gload_lds16(ga + (long)i * 32 * K + kt, &As[(i * 256 + wid * 64) * 8]);
      gload_lds16(gb + (long)i * 32 * K + kt, &Bs[(i * 256 + wid * 64) * 8]);
    }
    __syncthreads();
#pragma unroll
    for (int kk = 0; kk < 2; ++kk) {
      const int ko = kk * 32 + lg * 8;
      bf16x8 af[4], bf[4];
#pragma unroll
      for (int m = 0; m < 4; ++m)
        af[m] = *(const bf16x8*)&As[(wr + m * 16 + l16) * 64 + ko];
#pragma unroll
      for (int n = 0; n < 4; ++n)
        bf[n] = *(const bf16x8*)&Bs[(wc + n * 16 + l16) * 64 + ko];
#pragma unroll
      for (int m = 0; m < 4; ++m)
#pragma unroll
        for (int n = 0; n < 4; ++n)
          acc[m][n] = __builtin_amdgcn_mfma_f32_16x16x32_bf16(af[m], bf[n], acc[m][n], 0, 0, 0);
    }
  }

#pragma unroll
  for (int n = 0; n < 4; ++n) {
    const int col = bcol + wc + n * 16 + l16;
    const float bb = bias[col];
#pragma unroll
    for (int m = 0; m < 4; ++m) {
#pragma unroll
      for (int j = 0; j < 4; ++j) {
        const long row = brow + wr + m * 16 + lg * 4 + j;
        float vv = acc[m][n][j] + bb;
        if (HAS_GELU) vv = gelu_f(vv);
        if (HAS_RES) vv += res[row * N + col];
        if (OUT_BF16) ((short*)out)[row * N + col] = f2bf(vv);
        else          ((float*)out)[row * N + col] = vv;
      }
    }
  }
}

// --------------------------- causal flash attention -------------------------
// q,k,v,o: bf16 [B*S, D] with head h at cols [h*64, h*64+64).
// Block: 128 q-rows of one (b,h); 4 waves x 32 rows. K/V tiles of 64 keys.
// All LDS structures XOR-swizzled (T2) to kill 128B-stride bank conflicts:
//   Ks: swizzle on global SOURCE addr (global_load_lds dest must be linear)
//       + same XOR on read:  col ^= (row&7)<<3   (shorts)
//   Vt: write+read XOR:      key ^= ((dh&7)^((dh>>3)&7))<<3
//       (field mixes both dh axes so writes (vary dh>>3) AND reads (vary dh&7)
//        each spread across 8 bank slots)
//   Ps: write+read XOR:      col ^= (prow&7)<<3
__global__ __launch_bounds__(256, 2)
void attn_fwd(const short* __restrict__ q, const short* __restrict__ k,
              const short* __restrict__ v, short* __restrict__ o,
              int S, int D, int H) {
  const int tid = threadIdx.x, wid = tid >> 6, lane = tid & 63;
  const int l16 = lane & 15, lg = lane >> 4;
  const int h = blockIdx.y % H, bidx = blockIdx.y / H;
  // reversed: longest (largest q0) blocks dispatch first -> smaller tail
  const int q0 = (gridDim.x - 1 - blockIdx.x) * 128;
  const long base = (long)bidx * S * D + h * 64;

  __shared__ short Ks[64 * 64];
  __shared__ short Vt[64 * 64];       // transposed: Vt[dh][key], swizzled
  __shared__ short Ps[4][32 * 64];    // per-wave P tile, swizzled

  const int qw = q0 + wid * 32;

  bf16x8 qf[2][2];
#pragma unroll
  for (int m = 0; m < 2; ++m)
#pragma unroll
    for (int kk = 0; kk < 2; ++kk)
      qf[m][kk] = *(const bf16x8*)&q[base + (long)(qw + m * 16 + l16) * D + kk * 32 + lg * 8];

  f32x4 oa[2][4] = {};
  float mr[2][4], lr[2][4];
#pragma unroll
  for (int m = 0; m < 2; ++m)
#pragma unroll
    for (int j = 0; j < 4; ++j) { mr[m][j] = -1e30f; lr[m][j] = 0.f; }

  const int ntiles = q0 / 64 + 2;
  for (int t = 0; t < ntiles; ++t) {
    const int k0 = t * 64;
    __syncthreads();
    // stage K via global_load_lds: linear LDS dest, swizzled global source
#pragma unroll
    for (int i = 0; i < 2; ++i) {
      const int c = i * 256 + tid;
      const int row = c >> 3;                       // key 0..63
      const int col = ((c & 7) * 8) ^ ((row & 7) << 3);  // swizzled k-elem
      gload_lds16(&k[base + (long)(k0 + row) * D + col], &Ks[(i * 256 + wid * 64) * 8]);
    }
    // stage V transposed with swizzled writes
#pragma unroll
    for (int i = 0; i < 2; ++i) {
      const int c = i * 256 + tid;
      const int row = c >> 3;                       // key 0..63
      const int g8 = c & 7;
      bf16x8 vv = *(const bf16x8*)&v[base + (long)(k0 + row) * D + g8 * 8];
#pragma unroll
      for (int j = 0; j < 8; ++j) {
        const int dh = g8 * 8 + j;
        Vt[dh * 64 + (row ^ ((j ^ g8) << 3))] = vv[j];
      }
    }
    __syncthreads();

    // S = Q K^T
    f32x4 sf[2][4] = {};
#pragma unroll
    for (int kk = 0; kk < 2; ++kk) {
      const int ko = kk * 32 + lg * 8;
      bf16x8 kf[4];
#pragma unroll
      for (int n = 0; n < 4; ++n) {
        const int row = n * 16 + l16;
        kf[n] = *(const bf16x8*)&Ks[row * 64 + (ko ^ ((row & 7) << 3))];
      }
#pragma unroll
      for (int m = 0; m < 2; ++m)
#pragma unroll
        for (int n = 0; n < 4; ++n)
          sf[m][n] = __builtin_amdgcn_mfma_f32_16x16x32_bf16(qf[m][kk], kf[n], sf[m][n], 0, 0, 0);
    }

    const bool need_mask = (k0 + 64 > qw);
#pragma unroll
    for (int m = 0; m < 2; ++m) {
#pragma unroll
      for (int j = 0; j < 4; ++j) {
        const int prow = m * 16 + lg * 4 + j;
        const int qi = qw + prow - m * 16 + m * 16;  // = qw + m*16 + lg*4 + j
        float rm = -1e30f;
#pragma unroll
        for (int n = 0; n < 4; ++n) {
          float val = sf[m][n][j] * 0.125f;
          if (need_mask) {
            const int key = k0 + n * 16 + l16;
            if (key > qw + m * 16 + lg * 4 + j) val = -1e30f;
          }
          sf[m][n][j] = val;
          rm = fmaxf(rm, val);
        }
        rm = fmaxf(rm, __shfl_xor(rm, 1));
        rm = fmaxf(rm, __shfl_xor(rm, 2));
        rm = fmaxf(rm, __shfl_xor(rm, 4));
        rm = fmaxf(rm, __shfl_xor(rm, 8));
        const float mn = fmaxf(mr[m][j], rm);
        const float alpha = __expf(mr[m][j] - mn);
        mr[m][j] = mn;
        lr[m][j] *= alpha;
        float ps = 0.f;
#pragma unroll
        for (int n = 0; n < 4; ++n) {
          const float p = __expf(sf[m][n][j] - mn);
          ps += p;
          Ps[wid][prow * 64 + ((n * 16 + l16) ^ ((prow & 7) << 3))] = f2bf(p);
        }
        ps += __shfl_xor(ps, 1);
        ps += __shfl_xor(ps, 2);
        ps += __shfl_xor(ps, 4);
        ps += __shfl_xor(ps, 8);
        lr[m][j] += ps;
#pragma unroll
        for (int n = 0; n < 4; ++n) oa[m][n][j] *= alpha;
      }
    }

    // O += P V  (wave-local Ps, no barrier; LDS ops in-order per wave)
#pragma unroll
    for (int kk = 0; kk < 2; ++kk) {
      const int ko = kk * 32 + lg * 8;
      bf16x8 pf[2], vf[4];
#pragma unroll
      for (int m = 0; m < 2; ++m)
        pf[m] = *(const bf16x8*)&Ps[wid][(m * 16 + l16) * 64 + (ko ^ ((l16 & 7) << 3))];
#pragma unroll
      for (int n = 0; n < 4; ++n) {
        const int dh = n * 16 + l16;
        const int xf = ((dh & 7) ^ ((dh >> 3) & 7)) << 3;
        vf[n] = *(const bf16x8*)&Vt[dh * 64 + (ko ^ xf)];
      }
#pragma unroll
      for (int m = 0; m < 2; ++m)
#pragma unroll
        for (int n = 0; n < 4; ++n)
          oa[m][n] = __builtin_amdgcn_mfma_f32_16x16x32_bf16(pf[m], vf[n], oa[m][n], 0, 0, 0);
    }
  }

  // epilogue: O /= l, store bf16
#pragma unroll
  for (int m = 0; m < 2; ++m)
#pragma unroll
    for (int j = 0; j < 4; ++j) {
      const float inv = 1.f / lr[m][j];
      const long row = qw + m * 16 + lg * 4 + j;
#pragma unroll
      for (int n = 0; n < 4; ++n)
        o[base + row * D + n * 16 + l16] = f2bf(oa[m][n][j] * inv);
    }
}

// ------------------------------- launcher -----------------------------------
extern "C" void kernel_launch(void* const* d_in, const int* in_sizes, int n_in,
                              void* d_out, int out_size, void* d_ws, size_t ws_size,
                              hipStream_t stream) {
  (void)in_sizes; (void)n_in; (void)out_size; (void)ws_size;
  const float* h     = (const float*)d_in[0];
  const float* ln1_g = (const float*)d_in[1];
  const float* ln1_b = (const float*)d_in[2];
  const float* wq    = (const float*)d_in[3];
  const float* bq    = (const float*)d_in[4];
  const float* wk    = (const float*)d_in[5];
  const float* bk    = (const float*)d_in[6];
  const float* wv    = (const float*)d_in[7];
  const float* bv    = (const float*)d_in[8];
  const float* wo    = (const float*)d_in[9];
  const float* bo    = (const float*)d_in[10];
  const float* ln2_g = (const float*)d_in[11];
  const float* ln2_b = (const float*)d_in[12];
  const float* wfc   = (const float*)d_in[13];
  const float* bfc   = (const float*)d_in[14];
  const float* wproj = (const float*)d_in[15];
  const float* bproj = (const float*)d_in[16];

  const int B = 4, S = 2048, D = 1024, H = 16, F = 4096, T = B * S;

  char* ws = (char*)d_ws;
  size_t off = 0;
  auto alloc = [&](size_t bytes) {
    void* p = ws + off;
    off += (bytes + 255) & ~(size_t)255;
    return p;
  };
  short* xb  = (short*)alloc((size_t)T * D * 2);   // x1 / x2 (reused)
  short* qb  = (short*)alloc((size_t)T * D * 2);
  short* kb  = (short*)alloc((size_t)T * D * 2);
  short* vb  = (short*)alloc((size_t)T * D * 2);
  short* ob  = (short*)alloc((size_t)T * D * 2);
  float* h2  = (float*)alloc((size_t)T * D * 4);
  short* wqb = (short*)alloc((size_t)D * D * 2);
  short* wkb = (short*)alloc((size_t)D * D * 2);
  short* wvb = (short*)alloc((size_t)D * D * 2);
  short* wob = (short*)alloc((size_t)D * D * 2);
  short* wfcb   = (short*)alloc((size_t)F * D * 2);
  short* wprojb = (short*)alloc((size_t)D * F * 2);
  short* ub = qb;  // u [T,F] bf16 aliases q/k/v/o (contiguous, dead by FC time)

  cvt_f32_bf16<<<dim3(D * D / 4 / 256), 256, 0, stream>>>(wq, wqb, D * D / 4);
  cvt_f32_bf16<<<dim3(D * D / 4 / 256), 256, 0, stream>>>(wk, wkb, D * D / 4);
  cvt_f32_bf16<<<dim3(D * D / 4 / 256), 256, 0, stream>>>(wv, wvb, D * D / 4);
  cvt_f32_bf16<<<dim3(D * D / 4 / 256), 256, 0, stream>>>(wo, wob, D * D / 4);
  cvt_f32_bf16<<<dim3(F * D / 4 / 256), 256, 0, stream>>>(wfc, wfcb, F * D / 4);
  cvt_f32_bf16<<<dim3(D * F / 4 / 256), 256, 0, stream>>>(wproj, wprojb, D * F / 4);

  // attention sub-block
  ln_fwd<<<dim3(T), 256, 0, stream>>>(h, ln1_g, ln1_b, xb);
  gemm_bt<1, 0, 0><<<dim3(D / 128, T / 128), 256, 0, stream>>>(xb, wqb, bq, nullptr, qb, T, D, D);
  gemm_bt<1, 0, 0><<<dim3(D / 128, T / 128), 256, 0, stream>>>(xb, wkb, bk, nullptr, kb, T, D, D);
  gemm_bt<1, 0, 0><<<dim3(D / 128, T / 128), 256, 0, stream>>>(xb, wvb, bv, nullptr, vb, T, D, D);
  attn_fwd<<<dim3(S / 128, B * H), 256, 0, stream>>>(qb, kb, vb, ob, S, D, H);
  gemm_bt<0, 1, 0><<<dim3(D / 128, T / 128), 256, 0, stream>>>(ob, wob, bo, h, h2, T, D, D);

  // MLP sub-block
  ln_fwd<<<dim3(T), 256, 0, stream>>>(h2, ln2_g, ln2_b, xb);
  gemm_bt<1, 0, 1><<<dim3(F / 128, T / 128), 256, 0, stream>>>(xb, wfcb, bfc, nullptr, ub, T, F, D);
  gemm_bt<0, 1, 0><<<dim3(D / 128, T / 128), 256, 0, stream>>>(ub, wprojb, bproj, h2, (float*)d_out, T, D, F);
}

// Round 3
// 502.144 us; speedup vs baseline: 1.3189x; 1.1820x over previous
//
#include <hip/hip_runtime.h>
#include <hip/hip_bf16.h>
#include <stdint.h>

// ---------------------------------------------------------------------------
// GPT-2 block on MI355X (gfx950). Round 3: attention rewrite — swapped-QK^T
// in-register softmax (m214 structure): 32x32x16 MFMA, P never touches LDS,
// in-lane max/sum trees + one shfl_xor(32), cvt_pk_bf16 P-fragments,
// defer-max (T13), V pre-transposed globally so K and V both stage via
// global_load_lds with swizzled source. LDS 16KB/block.
// ---------------------------------------------------------------------------

typedef short bf16x8 __attribute__((ext_vector_type(8)));
typedef float f32x4  __attribute__((ext_vector_type(4)));
typedef float f32x16 __attribute__((ext_vector_type(16)));
typedef short s16x4  __attribute__((ext_vector_type(4)));

__device__ __forceinline__ short f2bf(float f) {
  union { float f; uint32_t u; } a;
  a.f = f;
  uint32_t r = a.u + 0x7fffu + ((a.u >> 16) & 1u);  // RNE
  return (short)(r >> 16);
}

__device__ __forceinline__ unsigned cvt_pk_bf16(float lo, float hi_) {
  unsigned r;
  asm("v_cvt_pk_bf16_f32 %0, %1, %2" : "=v"(r) : "v"(lo), "v"(hi_));
  return r;
}

__device__ __forceinline__ void gload_lds16(const void* g, void* l) {
  __builtin_amdgcn_global_load_lds(
      (const __attribute__((address_space(1))) void*)g,
      (__attribute__((address_space(3))) void*)l, 16, 0, 0);
}

__device__ __forceinline__ float gelu_f(float x) {
  float y = 0.7978845608028654f * (x + 0.044715f * x * x * x);
  y = fminf(fmaxf(y, -20.f), 20.f);
  float e = __expf(2.f * y);
  return 0.5f * x * (1.f + (e - 1.f) / (e + 1.f));  // tanh via exp
}

// --------------------------- weight fp32 -> bf16 ---------------------------
__global__ __launch_bounds__(256)
void cvt_f32_bf16(const float* __restrict__ in, short* __restrict__ out, int n4) {
  int i = blockIdx.x * 256 + threadIdx.x;
  if (i < n4) {
    float4 v = ((const float4*)in)[i];
    s16x4 o;
    o[0] = f2bf(v.x); o[1] = f2bf(v.y); o[2] = f2bf(v.z); o[3] = f2bf(v.w);
    ((s16x4*)out)[i] = o;
  }
}

// ------------------------------- LayerNorm ---------------------------------
__global__ __launch_bounds__(256)
void ln_fwd(const float* __restrict__ x, const float* __restrict__ g,
            const float* __restrict__ b, short* __restrict__ y) {
  const long row = blockIdx.x;
  const int t = threadIdx.x;
  const float4 xv = ((const float4*)(x + row * 1024))[t];
  float s  = xv.x + xv.y + xv.z + xv.w;
  float ss = xv.x * xv.x + xv.y * xv.y + xv.z * xv.z + xv.w * xv.w;
#pragma unroll
  for (int m = 1; m < 64; m <<= 1) {
    s  += __shfl_xor(s, m);
    ss += __shfl_xor(ss, m);
  }
  __shared__ float rs[4], rss[4];
  const int wid = t >> 6, lane = t & 63;
  if (lane == 0) { rs[wid] = s; rss[wid] = ss; }
  __syncthreads();
  s  = rs[0] + rs[1] + rs[2] + rs[3];
  ss = rss[0] + rss[1] + rss[2] + rss[3];
  const float mu   = s * (1.f / 1024.f);
  const float var  = ss * (1.f / 1024.f) - mu * mu;
  const float rstd = rsqrtf(var + 1e-5f);
  const float4 gv = ((const float4*)g)[t];
  const float4 bv = ((const float4*)b)[t];
  s16x4 ov;
  ov[0] = f2bf((xv.x - mu) * rstd * gv.x + bv.x);
  ov[1] = f2bf((xv.y - mu) * rstd * gv.y + bv.y);
  ov[2] = f2bf((xv.z - mu) * rstd * gv.z + bv.z);
  ov[3] = f2bf((xv.w - mu) * rstd * gv.w + bv.w);
  *(s16x4*)(y + row * 1024 + t * 4) = ov;
}

// ------------------------------- GEMM (NT) ----------------------------------
// C[M,N] = A[M,K](bf16) . W[N,K](bf16)^T + bias (+res) (+gelu)
template <int OUT_BF16, int HAS_RES, int HAS_GELU>
__global__ __launch_bounds__(256, 2)
void gemm_bt(const short* __restrict__ A, const short* __restrict__ W,
             const float* __restrict__ bias, const float* __restrict__ res,
             void* __restrict__ out, int M, int N, int K) {
  __shared__ short As[128 * 64];
  __shared__ short Bs[128 * 64];
  const int tid = threadIdx.x;
  const int wid = tid >> 6, lane = tid & 63;
  const int l16 = lane & 15, lg = lane >> 4;
  const int brow = blockIdx.y * 128, bcol = blockIdx.x * 128;
  const int wr = (wid >> 1) * 64, wc = (wid & 1) * 64;

  f32x4 acc[4][4] = {};

  const int r0 = tid >> 3;
  const int e8 = (tid & 7) * 8;
  const short* ga = A + (long)(brow + r0) * K + e8;
  const short* gb = W + (long)(bcol + r0) * K + e8;

  for (int kt = 0; kt < K; kt += 64) {
    __syncthreads();
#pragma unroll
    for (int i = 0; i < 4; ++i) {
      gload_lds16(ga + (long)i * 32 * K + kt, &As[(i * 256 + wid * 64) * 8]);
      gload_lds16(gb + (long)i * 32 * K + kt, &Bs[(i * 256 + wid * 64) * 8]);
    }
    __syncthreads();
#pragma unroll
    for (int kk = 0; kk < 2; ++kk) {
      const int ko = kk * 32 + lg * 8;
      bf16x8 af[4], bf[4];
#pragma unroll
      for (int m = 0; m < 4; ++m)
        af[m] = *(const bf16x8*)&As[(wr + m * 16 + l16) * 64 + ko];
#pragma unroll
      for (int n = 0; n < 4; ++n)
        bf[n] = *(const bf16x8*)&Bs[(wc + n * 16 + l16) * 64 + ko];
#pragma unroll
      for (int m = 0; m < 4; ++m)
#pragma unroll
        for (int n = 0; n < 4; ++n)
          acc[m][n] = __builtin_amdgcn_mfma_f32_16x16x32_bf16(af[m], bf[n], acc[m][n], 0, 0, 0);
    }
  }

#pragma unroll
  for (int n = 0; n < 4; ++n) {
    const int col = bcol + wc + n * 16 + l16;
    const float bb = bias[col];
#pragma unroll
    for (int m = 0; m < 4; ++m) {
#pragma unroll
      for (int j = 0; j < 4; ++j) {
        const long row = brow + wr + m * 16 + lg * 4 + j;
        float vv = acc[m][n][j] + bb;
        if (HAS_GELU) vv = gelu_f(vv);
        if (HAS_RES) vv += res[row * N + col];
        if (OUT_BF16) ((short*)out)[row * N + col] = f2bf(vv);
        else          ((float*)out)[row * N + col] = vv;
      }
    }
  }
}

// ------------------------- V transpose (per head) ---------------------------
// vb [B*S, D] (head h cols) -> vtg [(b*H+h)*64 + dh][S]
__global__ __launch_bounds__(256)
void transpose_v(const short* __restrict__ v, short* __restrict__ vtg,
                 int S, int D, int H) {
  __shared__ short t[64][66];   // pad 2 shorts: row stride 33 words, spreads banks
  const int bh = blockIdx.y, b = bh / H, hh = bh % H;
  const int s0 = blockIdx.x * 64;
  const int tid = threadIdx.x;
#pragma unroll
  for (int i = 0; i < 2; ++i) {
    const int c = i * 256 + tid;
    const int sl = c >> 3, d8 = (c & 7) * 8;
    bf16x8 vv = *(const bf16x8*)&v[((long)b * S + s0 + sl) * D + hh * 64 + d8];
#pragma unroll
    for (int j = 0; j < 8; ++j) t[d8 + j][sl] = vv[j];
  }
  __syncthreads();
#pragma unroll
  for (int i = 0; i < 2; ++i) {
    const int c = i * 256 + tid;
    const int dl = c >> 3, s8 = (c & 7) * 8;
    bf16x8 ov;
#pragma unroll
    for (int j = 0; j < 8; ++j) ov[j] = t[dl][s8 + j];
    *(bf16x8*)&vtg[((long)bh * 64 + dl) * S + s0 + s8] = ov;
  }
}

// --------------------------- causal flash attention -------------------------
// Swapped QK^T: St[key][q] = mfma(K_frag, Q_frag) so each lane owns the P
// values of q-row (lane&31). Softmax fully in-register (tree + shfl_xor(32)).
// P -> bf16 A-fragments via v_cvt_pk_bf16_f32 + cross-half exchange.
// K tile [key][dh] and V tile [dh][key] both staged via global_load_lds with
// source-swizzled granules (granule ^= row&7) for conflict-reduced b128 reads.
__global__ __launch_bounds__(256, 2)
void attn_fwd2(const short* __restrict__ qg, const short* __restrict__ kg,
               const short* __restrict__ vtg, short* __restrict__ og,
               int S, int D, int H) {
  const int tid = threadIdx.x, wid = tid >> 6, lane = tid & 63;
  const int l31 = lane & 31, hi = lane >> 5;
  const int bh = blockIdx.y;
  const int b = bh / H, hh = bh % H;
  const int q0 = ((int)gridDim.x - 1 - (int)blockIdx.x) * 128;  // long blocks first
  const long qbase = ((long)b * S) * D + hh * 64;
  const long vbase = (long)bh * 64 * S;

  __shared__ short Ks[64 * 64];
  __shared__ short Vs[64 * 64];

  const int qw = q0 + wid * 32;
  const int qv = qw + l31;

  // Q B-fragments: lane holds Q[q=qv][d = 16s + 8*hi + 0..7]
  bf16x8 qf[4];
#pragma unroll
  for (int s = 0; s < 4; ++s)
    qf[s] = *(const bf16x8*)&qg[qbase + (long)qv * D + 16 * s + 8 * hi];

  f32x16 oa[2] = {};          // O[q=crow(r,hi)][dh = 32*nb + l31]
  float mr = -3000.f, lr = 0.f;  // per q-row (lane&31), duplicated across halves

  const int ntiles = q0 / 64 + 2;
  for (int t = 0; t < ntiles; ++t) {
    const int k0 = t * 64;
    __syncthreads();
#pragma unroll
    for (int i = 0; i < 2; ++i) {
      const int c = i * 256 + tid;
      const int row = c >> 3, gl = c & 7;
      gload_lds16(&kg[qbase + (long)(k0 + row) * D + 8 * (gl ^ (row & 7))],
                  &Ks[(i * 256 + wid * 64) * 8]);
      gload_lds16(&vtg[vbase + (long)row * S + k0 + 8 * (gl ^ (row & 7))],
                  &Vs[(i * 256 + wid * 64) * 8]);
    }
    __syncthreads();

    if (k0 >= qw + 32) continue;   // tile fully masked for this wave

    // St[key][q] : 2 key-blocks x 4 d-slices
    f32x16 st[2] = {};
#pragma unroll
    for (int s = 0; s < 4; ++s) {
      const int g = ((s << 1) | hi) ^ (l31 & 7);
      bf16x8 kf0 = *(const bf16x8*)&Ks[l31 * 64 + 8 * g];
      bf16x8 kf1 = *(const bf16x8*)&Ks[(32 + l31) * 64 + 8 * g];
      st[0] = __builtin_amdgcn_mfma_f32_32x32x16_bf16(kf0, qf[s], st[0], 0, 0, 0);
      st[1] = __builtin_amdgcn_mfma_f32_32x32x16_bf16(kf1, qf[s], st[1], 0, 0, 0);
    }

    // scale + causal mask; lane holds P[q=qv][key = k0+32kb+crow(r,hi)]
    const bool need_mask = (k0 + 63 > qw);
    float pv[2][16];
#pragma unroll
    for (int kb = 0; kb < 2; ++kb)
#pragma unroll
      for (int r = 0; r < 16; ++r) {
        float v = st[kb][r] * 0.125f;
        if (need_mask) {
          const int key = k0 + kb * 32 + (r & 3) + 8 * (r >> 2) + 4 * hi;
          if (key > qv) v = -1e30f;
        }
        pv[kb][r] = v;
      }

    // row max: in-lane tree + one cross-half exchange
    float t8[8];
#pragma unroll
    for (int j = 0; j < 8; ++j)
      t8[j] = fmaxf(fmaxf(pv[0][j], pv[0][8 + j]), fmaxf(pv[1][j], pv[1][8 + j]));
    float rm = fmaxf(fmaxf(fmaxf(t8[0], t8[1]), fmaxf(t8[2], t8[3])),
                     fmaxf(fmaxf(t8[4], t8[5]), fmaxf(t8[6], t8[7])));
    rm = fmaxf(rm, __shfl_xor(rm, 32));

    // defer-max (T13): skip rescale while growth <= 8
    const bool defer = (bool)__all(rm <= mr + 8.f);
    const float mn = defer ? mr : fmaxf(mr, rm);

    float a0 = 0.f, a1 = 0.f, a2 = 0.f, a3 = 0.f;
#pragma unroll
    for (int r = 0; r < 8; ++r) {
      float p0 = __expf(pv[0][r] - mn);      pv[0][r] = p0;      a0 += p0;
      float p1 = __expf(pv[0][8 + r] - mn);  pv[0][8 + r] = p1;  a1 += p1;
      float p2 = __expf(pv[1][r] - mn);      pv[1][r] = p2;      a2 += p2;
      float p3 = __expf(pv[1][8 + r] - mn);  pv[1][8 + r] = p3;  a3 += p3;
    }
    float ls = (a0 + a1) + (a2 + a3);
    ls += __shfl_xor(ls, 32);

    if (!defer) {
      const float alpha = __expf(mr - mn);
      lr = lr * alpha + ls;
      mr = mn;
#pragma unroll
      for (int r = 0; r < 16; ++r) {
        const int crow = (r & 3) + 8 * (r >> 2) + 4 * hi;
        const float ar = __shfl(alpha, crow | (lane & 32));
        oa[0][r] *= ar;
        oa[1][r] *= ar;
      }
    } else {
      lr += ls;
    }

    // P -> bf16 A-fragments (keys 16s+8hi+0..7 per slice s)
    bf16x8 pa[4];
#pragma unroll
    for (int kb = 0; kb < 2; ++kb) {
      unsigned pk[8], ex[8];
#pragma unroll
      for (int i2 = 0; i2 < 8; ++i2)
        pk[i2] = cvt_pk_bf16(pv[kb][2 * i2], pv[kb][2 * i2 + 1]);
#pragma unroll
      for (int i2 = 0; i2 < 8; ++i2)
        ex[i2] = (unsigned)__shfl_xor((int)pk[i2], 32);
      union { unsigned u[4]; bf16x8 v8; } f0, f1;
      f0.u[0] = hi ? ex[2] : pk[0];
      f0.u[1] = hi ? ex[3] : pk[1];
      f0.u[2] = hi ? pk[2] : ex[0];
      f0.u[3] = hi ? pk[3] : ex[1];
      f1.u[0] = hi ? ex[6] : pk[4];
      f1.u[1] = hi ? ex[7] : pk[5];
      f1.u[2] = hi ? pk[6] : ex[4];
      f1.u[3] = hi ? pk[7] : ex[5];
      pa[2 * kb]     = f0.v8;
      pa[2 * kb + 1] = f1.v8;
    }

    // O += P V : B-frag lane reads Vs[dh = 32nb + l31][keys 16s+8hi..+7]
#pragma unroll
    for (int s = 0; s < 4; ++s) {
      const int g = ((s << 1) | hi) ^ (l31 & 7);
      bf16x8 vf0 = *(const bf16x8*)&Vs[l31 * 64 + 8 * g];
      bf16x8 vf1 = *(const bf16x8*)&Vs[(32 + l31) * 64 + 8 * g];
      oa[0] = __builtin_amdgcn_mfma_f32_32x32x16_bf16(pa[s], vf0, oa[0], 0, 0, 0);
      oa[1] = __builtin_amdgcn_mfma_f32_32x32x16_bf16(pa[s], vf1, oa[1], 0, 0, 0);
    }
  }

  // epilogue: O /= l (l redistributed to reg-q domain), store bf16
  const float linv = 1.f / lr;
#pragma unroll
  for (int r = 0; r < 16; ++r) {
    const int crow = (r & 3) + 8 * (r >> 2) + 4 * hi;
    const float li = __shfl(linv, crow | (lane & 32));
    const long row = qw + crow;
    og[qbase + row * D + l31]      = f2bf(oa[0][r] * li);
    og[qbase + row * D + 32 + l31] = f2bf(oa[1][r] * li);
  }
}

// ------------------------------- launcher -----------------------------------
extern "C" void kernel_launch(void* const* d_in, const int* in_sizes, int n_in,
                              void* d_out, int out_size, void* d_ws, size_t ws_size,
                              hipStream_t stream) {
  (void)in_sizes; (void)n_in; (void)out_size; (void)ws_size;
  const float* h     = (const float*)d_in[0];
  const float* ln1_g = (const float*)d_in[1];
  const float* ln1_b = (const float*)d_in[2];
  const float* wq    = (const float*)d_in[3];
  const float* bq    = (const float*)d_in[4];
  const float* wk    = (const float*)d_in[5];
  const float* bk    = (const float*)d_in[6];
  const float* wv    = (const float*)d_in[7];
  const float* bv    = (const float*)d_in[8];
  const float* wo    = (const float*)d_in[9];
  const float* bo    = (const float*)d_in[10];
  const float* ln2_g = (const float*)d_in[11];
  const float* ln2_b = (const float*)d_in[12];
  const float* wfc   = (const float*)d_in[13];
  const float* bfc   = (const float*)d_in[14];
  const float* wproj = (const float*)d_in[15];
  const float* bproj = (const float*)d_in[16];

  const int B = 4, S = 2048, D = 1024, H = 16, F = 4096, T = B * S;

  char* ws = (char*)d_ws;
  size_t off = 0;
  auto alloc = [&](size_t bytes) {
    void* p = ws + off;
    off += (bytes + 255) & ~(size_t)255;
    return p;
  };
  short* xb  = (short*)alloc((size_t)T * D * 2);   // x1 / x2 (reused)
  short* qb  = (short*)alloc((size_t)T * D * 2);
  short* kb  = (short*)alloc((size_t)T * D * 2);
  short* vb  = (short*)alloc((size_t)T * D * 2);
  short* ob  = (short*)alloc((size_t)T * D * 2);
  float* h2  = (float*)alloc((size_t)T * D * 4);
  short* wqb = (short*)alloc((size_t)D * D * 2);
  short* wkb = (short*)alloc((size_t)D * D * 2);
  short* wvb = (short*)alloc((size_t)D * D * 2);
  short* wob = (short*)alloc((size_t)D * D * 2);
  short* wfcb   = (short*)alloc((size_t)F * D * 2);
  short* wprojb = (short*)alloc((size_t)D * F * 2);
  short* ub  = qb;            // u [T,F] bf16 aliases q/k/v/o (dead by FC time)
  short* vtg = (short*)h2;    // V^T [B*H*64, S] aliases h2 (dead before Wo writes h2)

  cvt_f32_bf16<<<dim3(D * D / 4 / 256), 256, 0, stream>>>(wq, wqb, D * D / 4);
  cvt_f32_bf16<<<dim3(D * D / 4 / 256), 256, 0, stream>>>(wk, wkb, D * D / 4);
  cvt_f32_bf16<<<dim3(D * D / 4 / 256), 256, 0, stream>>>(wv, wvb, D * D / 4);
  cvt_f32_bf16<<<dim3(D * D / 4 / 256), 256, 0, stream>>>(wo, wob, D * D / 4);
  cvt_f32_bf16<<<dim3(F * D / 4 / 256), 256, 0, stream>>>(wfc, wfcb, F * D / 4);
  cvt_f32_bf16<<<dim3(D * F / 4 / 256), 256, 0, stream>>>(wproj, wprojb, D * F / 4);

  // attention sub-block
  ln_fwd<<<dim3(T), 256, 0, stream>>>(h, ln1_g, ln1_b, xb);
  gemm_bt<1, 0, 0><<<dim3(D / 128, T / 128), 256, 0, stream>>>(xb, wqb, bq, nullptr, qb, T, D, D);
  gemm_bt<1, 0, 0><<<dim3(D / 128, T / 128), 256, 0, stream>>>(xb, wkb, bk, nullptr, kb, T, D, D);
  gemm_bt<1, 0, 0><<<dim3(D / 128, T / 128), 256, 0, stream>>>(xb, wvb, bv, nullptr, vb, T, D, D);
  transpose_v<<<dim3(S / 64, B * H), 256, 0, stream>>>(vb, vtg, S, D, H);
  attn_fwd2<<<dim3(S / 128, B * H), 256, 0, stream>>>(qb, kb, vtg, ob, S, D, H);
  gemm_bt<0, 1, 0><<<dim3(D / 128, T / 128), 256, 0, stream>>>(ob, wob, bo, h, h2, T, D, D);

  // MLP sub-block
  ln_fwd<<<dim3(T), 256, 0, stream>>>(h2, ln2_g, ln2_b, xb);
  gemm_bt<1, 0, 1><<<dim3(F / 128, T / 128), 256, 0, stream>>>(xb, wfcb, bfc, nullptr, ub, T, F, D);
  gemm_bt<0, 1, 0><<<dim3(D / 128, T / 128), 256, 0, stream>>>(ub, wprojb, bproj, h2, (float*)d_out, T, D, F);
}

// Round 4
// 474.294 us; speedup vs baseline: 1.3964x; 1.0587x over previous
//
#include <hip/hip_runtime.h>
#include <hip/hip_bf16.h>
#include <stdint.h>

// ---------------------------------------------------------------------------
// GPT-2 block on MI355X (gfx950). Round 4:
//  - attn: 4 blocks/CU occupancy + double-buffered K/V staging with counted
//    vmcnt (T3/T4-lite) and raw barrier pairs.
//  - FC GEMM: 256x256 tile, 512 thr / 8 waves (2x4), dbuf LDS 128KB, 8-way
//    granule XOR swizzle (source+read), counted vmcnt(8), setprio (T5),
//    XCD-aware block swizzle (T1). Other GEMMs stay on the 128² structure.
// ---------------------------------------------------------------------------

typedef short bf16x8 __attribute__((ext_vector_type(8)));
typedef float f32x4  __attribute__((ext_vector_type(4)));
typedef float f32x16 __attribute__((ext_vector_type(16)));
typedef short s16x4  __attribute__((ext_vector_type(4)));

__device__ __forceinline__ short f2bf(float f) {
  union { float f; uint32_t u; } a;
  a.f = f;
  uint32_t r = a.u + 0x7fffu + ((a.u >> 16) & 1u);  // RNE
  return (short)(r >> 16);
}

__device__ __forceinline__ unsigned cvt_pk_bf16(float lo, float hi_) {
  unsigned r;
  asm("v_cvt_pk_bf16_f32 %0, %1, %2" : "=v"(r) : "v"(lo), "v"(hi_));
  return r;
}

__device__ __forceinline__ void gload_lds16(const void* g, void* l) {
  __builtin_amdgcn_global_load_lds(
      (const __attribute__((address_space(1))) void*)g,
      (__attribute__((address_space(3))) void*)l, 16, 0, 0);
}

__device__ __forceinline__ float gelu_f(float x) {
  float y = 0.7978845608028654f * (x + 0.044715f * x * x * x);
  y = fminf(fmaxf(y, -20.f), 20.f);
  float e = __expf(2.f * y);
  return 0.5f * x * (1.f + (e - 1.f) / (e + 1.f));  // tanh via exp
}

// --------------------------- weight fp32 -> bf16 ---------------------------
__global__ __launch_bounds__(256)
void cvt_f32_bf16(const float* __restrict__ in, short* __restrict__ out, int n4) {
  int i = blockIdx.x * 256 + threadIdx.x;
  if (i < n4) {
    float4 v = ((const float4*)in)[i];
    s16x4 o;
    o[0] = f2bf(v.x); o[1] = f2bf(v.y); o[2] = f2bf(v.z); o[3] = f2bf(v.w);
    ((s16x4*)out)[i] = o;
  }
}

// ------------------------------- LayerNorm ---------------------------------
__global__ __launch_bounds__(256)
void ln_fwd(const float* __restrict__ x, const float* __restrict__ g,
            const float* __restrict__ b, short* __restrict__ y) {
  const long row = blockIdx.x;
  const int t = threadIdx.x;
  const float4 xv = ((const float4*)(x + row * 1024))[t];
  float s  = xv.x + xv.y + xv.z + xv.w;
  float ss = xv.x * xv.x + xv.y * xv.y + xv.z * xv.z + xv.w * xv.w;
#pragma unroll
  for (int m = 1; m < 64; m <<= 1) {
    s  += __shfl_xor(s, m);
    ss += __shfl_xor(ss, m);
  }
  __shared__ float rs[4], rss[4];
  const int wid = t >> 6, lane = t & 63;
  if (lane == 0) { rs[wid] = s; rss[wid] = ss; }
  __syncthreads();
  s  = rs[0] + rs[1] + rs[2] + rs[3];
  ss = rss[0] + rss[1] + rss[2] + rss[3];
  const float mu   = s * (1.f / 1024.f);
  const float var  = ss * (1.f / 1024.f) - mu * mu;
  const float rstd = rsqrtf(var + 1e-5f);
  const float4 gv = ((const float4*)g)[t];
  const float4 bv = ((const float4*)b)[t];
  s16x4 ov;
  ov[0] = f2bf((xv.x - mu) * rstd * gv.x + bv.x);
  ov[1] = f2bf((xv.y - mu) * rstd * gv.y + bv.y);
  ov[2] = f2bf((xv.z - mu) * rstd * gv.z + bv.z);
  ov[3] = f2bf((xv.w - mu) * rstd * gv.w + bv.w);
  *(s16x4*)(y + row * 1024 + t * 4) = ov;
}

// --------------------------- GEMM 128x128 (NT) ------------------------------
template <int OUT_BF16, int HAS_RES, int HAS_GELU>
__global__ __launch_bounds__(256, 2)
void gemm_bt(const short* __restrict__ A, const short* __restrict__ W,
             const float* __restrict__ bias, const float* __restrict__ res,
             void* __restrict__ out, int M, int N, int K) {
  __shared__ short As[128 * 64];
  __shared__ short Bs[128 * 64];
  const int tid = threadIdx.x;
  const int wid = tid >> 6, lane = tid & 63;
  const int l16 = lane & 15, lg = lane >> 4;
  const int brow = blockIdx.y * 128, bcol = blockIdx.x * 128;
  const int wr = (wid >> 1) * 64, wc = (wid & 1) * 64;

  f32x4 acc[4][4] = {};

  const int r0 = tid >> 3;
  const int e8 = (tid & 7) * 8;
  const short* ga = A + (long)(brow + r0) * K + e8;
  const short* gb = W + (long)(bcol + r0) * K + e8;

  for (int kt = 0; kt < K; kt += 64) {
    __syncthreads();
#pragma unroll
    for (int i = 0; i < 4; ++i) {
      gload_lds16(ga + (long)i * 32 * K + kt, &As[(i * 256 + wid * 64) * 8]);
      gload_lds16(gb + (long)i * 32 * K + kt, &Bs[(i * 256 + wid * 64) * 8]);
    }
    __syncthreads();
#pragma unroll
    for (int kk = 0; kk < 2; ++kk) {
      const int ko = kk * 32 + lg * 8;
      bf16x8 af[4], bf[4];
#pragma unroll
      for (int m = 0; m < 4; ++m)
        af[m] = *(const bf16x8*)&As[(wr + m * 16 + l16) * 64 + ko];
#pragma unroll
      for (int n = 0; n < 4; ++n)
        bf[n] = *(const bf16x8*)&Bs[(wc + n * 16 + l16) * 64 + ko];
#pragma unroll
      for (int m = 0; m < 4; ++m)
#pragma unroll
        for (int n = 0; n < 4; ++n)
          acc[m][n] = __builtin_amdgcn_mfma_f32_16x16x32_bf16(af[m], bf[n], acc[m][n], 0, 0, 0);
    }
  }

#pragma unroll
  for (int n = 0; n < 4; ++n) {
    const int col = bcol + wc + n * 16 + l16;
    const float bb = bias[col];
#pragma unroll
    for (int m = 0; m < 4; ++m) {
#pragma unroll
      for (int j = 0; j < 4; ++j) {
        const long row = brow + wr + m * 16 + lg * 4 + j;
        float vv = acc[m][n][j] + bb;
        if (HAS_GELU) vv = gelu_f(vv);
        if (HAS_RES) vv += res[row * N + col];
        if (OUT_BF16) ((short*)out)[row * N + col] = f2bf(vv);
        else          ((float*)out)[row * N + col] = vv;
      }
    }
  }
}

// --------------------------- GEMM 256x256 (NT) ------------------------------
// 512 threads, 8 waves (2M x 4N), per-wave output 128x64, BK=64, dbuf LDS.
// 8-way granule XOR swizzle: LDS granule slot g of row r holds global granule
// g ^ (r&7); staged with swizzled global source (linear LDS dest).
// Counted vmcnt(8): tile t+1's 8 loads stay in flight across the K-step.
template <int OUT_BF16, int HAS_RES, int HAS_GELU>
__global__ __launch_bounds__(512, 2)
void gemm_bt256(const short* __restrict__ A, const short* __restrict__ W,
                const float* __restrict__ bias, const float* __restrict__ res,
                void* __restrict__ out, int M, int N, int K) {
  __shared__ short As[2][256 * 64];
  __shared__ short Bs[2][256 * 64];
  const int tid = threadIdx.x;
  const int wid = tid >> 6, lane = tid & 63;
  const int l16 = lane & 15, lg = lane >> 4;
  const int wm = wid >> 2, wn = wid & 3;      // 2 x 4 wave grid

  // XCD-aware swizzle on flat block id (grid is a multiple of 8 here)
  const int nbx = N >> 8;
  const int nwg = nbx * (M >> 8);
  int flat = (int)blockIdx.y * nbx + (int)blockIdx.x;
  if ((nwg & 7) == 0) flat = (flat & 7) * (nwg >> 3) + (flat >> 3);
  const int brow = (flat / nbx) * 256, bcol = (flat % nbx) * 256;

  f32x4 acc[8][4] = {};

  const int r0 = tid >> 3, g0 = tid & 7;

  auto STAGE = [&](int buf, int kt) {
#pragma unroll
    for (int i = 0; i < 4; ++i) {
      const int row = i * 64 + r0;
      const int col = 8 * (g0 ^ (row & 7));
      gload_lds16(A + (long)(brow + row) * K + kt + col,
                  &As[buf][(i * 512 + wid * 64) * 8]);
    }
#pragma unroll
    for (int i = 0; i < 4; ++i) {
      const int row = i * 64 + r0;
      const int col = 8 * (g0 ^ (row & 7));
      gload_lds16(W + (long)(bcol + row) * K + kt + col,
                  &Bs[buf][(i * 512 + wid * 64) * 8]);
    }
  };

  const int NT = K >> 6;
  STAGE(0, 0);
  STAGE(1, 64);

  for (int t = 0; t < NT; ++t) {
    const int cur = t & 1;
    if (t < NT - 1) asm volatile("s_waitcnt vmcnt(8)" ::: "memory");
    else            asm volatile("s_waitcnt vmcnt(0)" ::: "memory");
    __builtin_amdgcn_s_barrier();

    // ds_read all fragments of tile t (24 x b128 per lane)
    bf16x8 af0[8], af1[8], bf0[4], bf1[4];
#pragma unroll
    for (int m = 0; m < 8; ++m) {
      const int r = wm * 128 + m * 16 + l16;
      af0[m] = *(const bf16x8*)&As[cur][r * 64 + 8 * (lg ^ (r & 7))];
      af1[m] = *(const bf16x8*)&As[cur][r * 64 + 8 * ((4 + lg) ^ (r & 7))];
    }
#pragma unroll
    for (int n = 0; n < 4; ++n) {
      const int r = wn * 64 + n * 16 + l16;
      bf0[n] = *(const bf16x8*)&Bs[cur][r * 64 + 8 * (lg ^ (r & 7))];
      bf1[n] = *(const bf16x8*)&Bs[cur][r * 64 + 8 * ((4 + lg) ^ (r & 7))];
    }

    __builtin_amdgcn_s_setprio(1);
#pragma unroll
    for (int m = 0; m < 8; ++m)
#pragma unroll
      for (int n = 0; n < 4; ++n)
        acc[m][n] = __builtin_amdgcn_mfma_f32_16x16x32_bf16(af0[m], bf0[n], acc[m][n], 0, 0, 0);
    __builtin_amdgcn_s_setprio(0);

    asm volatile("s_waitcnt lgkmcnt(0)" ::: "memory");  // all our buf[cur] reads done
    __builtin_amdgcn_s_barrier();                       // ... in every wave
    if (t + 2 < NT) STAGE(cur, (t + 2) * 64);           // safe to overwrite

    __builtin_amdgcn_s_setprio(1);
#pragma unroll
    for (int m = 0; m < 8; ++m)
#pragma unroll
      for (int n = 0; n < 4; ++n)
        acc[m][n] = __builtin_amdgcn_mfma_f32_16x16x32_bf16(af1[m], bf1[n], acc[m][n], 0, 0, 0);
    __builtin_amdgcn_s_setprio(0);
  }

#pragma unroll
  for (int n = 0; n < 4; ++n) {
    const int col = bcol + wn * 64 + n * 16 + l16;
    const float bb = bias[col];
#pragma unroll
    for (int m = 0; m < 8; ++m) {
#pragma unroll
      for (int j = 0; j < 4; ++j) {
        const long row = brow + wm * 128 + m * 16 + lg * 4 + j;
        float vv = acc[m][n][j] + bb;
        if (HAS_GELU) vv = gelu_f(vv);
        if (HAS_RES) vv += res[row * N + col];
        if (OUT_BF16) ((short*)out)[row * N + col] = f2bf(vv);
        else          ((float*)out)[row * N + col] = vv;
      }
    }
  }
}

// ------------------------- V transpose (per head) ---------------------------
__global__ __launch_bounds__(256)
void transpose_v(const short* __restrict__ v, short* __restrict__ vtg,
                 int S, int D, int H) {
  __shared__ short t[64][66];
  const int bh = blockIdx.y, b = bh / H, hh = bh % H;
  const int s0 = blockIdx.x * 64;
  const int tid = threadIdx.x;
#pragma unroll
  for (int i = 0; i < 2; ++i) {
    const int c = i * 256 + tid;
    const int sl = c >> 3, d8 = (c & 7) * 8;
    bf16x8 vv = *(const bf16x8*)&v[((long)b * S + s0 + sl) * D + hh * 64 + d8];
#pragma unroll
    for (int j = 0; j < 8; ++j) t[d8 + j][sl] = vv[j];
  }
  __syncthreads();
#pragma unroll
  for (int i = 0; i < 2; ++i) {
    const int c = i * 256 + tid;
    const int dl = c >> 3, s8 = (c & 7) * 8;
    bf16x8 ov;
#pragma unroll
    for (int j = 0; j < 8; ++j) ov[j] = t[dl][s8 + j];
    *(bf16x8*)&vtg[((long)bh * 64 + dl) * S + s0 + s8] = ov;
  }
}

// --------------------------- causal flash attention -------------------------
// Swapped QK^T in-register softmax (as round 3) + double-buffered K/V with
// counted vmcnt and 4 blocks/CU occupancy.
__global__ __launch_bounds__(256, 4)
void attn_fwd2(const short* __restrict__ qg, const short* __restrict__ kg,
               const short* __restrict__ vtg, short* __restrict__ og,
               int S, int D, int H) {
  const int tid = threadIdx.x, wid = tid >> 6, lane = tid & 63;
  const int l31 = lane & 31, hi = lane >> 5;
  const int bh = blockIdx.y;
  const int b = bh / H, hh = bh % H;
  const int q0 = ((int)gridDim.x - 1 - (int)blockIdx.x) * 128;  // long blocks first
  const long qbase = ((long)b * S) * D + hh * 64;
  const long vbase = (long)bh * 64 * S;

  __shared__ short Ks[2][64 * 64];
  __shared__ short Vs[2][64 * 64];

  const int qw = q0 + wid * 32;
  const int qv = qw + l31;

  bf16x8 qf[4];
#pragma unroll
  for (int s = 0; s < 4; ++s)
    qf[s] = *(const bf16x8*)&qg[qbase + (long)qv * D + 16 * s + 8 * hi];

  f32x16 oa[2] = {};
  float mr = -3000.f, lr = 0.f;

  const int ntiles = q0 / 64 + 2;

  auto STAGE = [&](int buf, int k0) {
#pragma unroll
    for (int i = 0; i < 2; ++i) {
      const int c = i * 256 + tid;
      const int row = c >> 3, gl = c & 7;
      gload_lds16(&kg[qbase + (long)(k0 + row) * D + 8 * (gl ^ (row & 7))],
                  &Ks[buf][(i * 256 + wid * 64) * 8]);
      gload_lds16(&vtg[vbase + (long)row * S + k0 + 8 * (gl ^ (row & 7))],
                  &Vs[buf][(i * 256 + wid * 64) * 8]);
    }
  };

  STAGE(0, 0);
  for (int t = 0; t < ntiles; ++t) {
    const int cur = t & 1;
    const int k0 = t * 64;
    if (t + 1 < ntiles) {
      STAGE(cur ^ 1, k0 + 64);
      asm volatile("s_waitcnt vmcnt(4)" ::: "memory");
    } else {
      asm volatile("s_waitcnt vmcnt(0)" ::: "memory");
    }
    __builtin_amdgcn_s_barrier();

    if (k0 < qw + 32) {   // tile not fully masked for this wave
      // St[key][q]
      f32x16 st[2] = {};
#pragma unroll
      for (int s = 0; s < 4; ++s) {
        const int g = ((s << 1) | hi) ^ (l31 & 7);
        bf16x8 kf0 = *(const bf16x8*)&Ks[cur][l31 * 64 + 8 * g];
        bf16x8 kf1 = *(const bf16x8*)&Ks[cur][(32 + l31) * 64 + 8 * g];
        st[0] = __builtin_amdgcn_mfma_f32_32x32x16_bf16(kf0, qf[s], st[0], 0, 0, 0);
        st[1] = __builtin_amdgcn_mfma_f32_32x32x16_bf16(kf1, qf[s], st[1], 0, 0, 0);
      }

      const bool need_mask = (k0 + 63 > qw);
      float pv[2][16];
#pragma unroll
      for (int kb = 0; kb < 2; ++kb)
#pragma unroll
        for (int r = 0; r < 16; ++r) {
          float v = st[kb][r] * 0.125f;
          if (need_mask) {
            const int key = k0 + kb * 32 + (r & 3) + 8 * (r >> 2) + 4 * hi;
            if (key > qv) v = -1e30f;
          }
          pv[kb][r] = v;
        }

      float t8[8];
#pragma unroll
      for (int j = 0; j < 8; ++j)
        t8[j] = fmaxf(fmaxf(pv[0][j], pv[0][8 + j]), fmaxf(pv[1][j], pv[1][8 + j]));
      float rm = fmaxf(fmaxf(fmaxf(t8[0], t8[1]), fmaxf(t8[2], t8[3])),
                       fmaxf(fmaxf(t8[4], t8[5]), fmaxf(t8[6], t8[7])));
      rm = fmaxf(rm, __shfl_xor(rm, 32));

      const bool defer = (bool)__all(rm <= mr + 8.f);
      const float mn = defer ? mr : fmaxf(mr, rm);

      float a0 = 0.f, a1 = 0.f, a2 = 0.f, a3 = 0.f;
#pragma unroll
      for (int r = 0; r < 8; ++r) {
        float p0 = __expf(pv[0][r] - mn);      pv[0][r] = p0;      a0 += p0;
        float p1 = __expf(pv[0][8 + r] - mn);  pv[0][8 + r] = p1;  a1 += p1;
        float p2 = __expf(pv[1][r] - mn);      pv[1][r] = p2;      a2 += p2;
        float p3 = __expf(pv[1][8 + r] - mn);  pv[1][8 + r] = p3;  a3 += p3;
      }
      float ls = (a0 + a1) + (a2 + a3);
      ls += __shfl_xor(ls, 32);

      if (!defer) {
        const float alpha = __expf(mr - mn);
        lr = lr * alpha + ls;
        mr = mn;
#pragma unroll
        for (int r = 0; r < 16; ++r) {
          const int crow = (r & 3) + 8 * (r >> 2) + 4 * hi;
          const float ar = __shfl(alpha, crow | (lane & 32));
          oa[0][r] *= ar;
          oa[1][r] *= ar;
        }
      } else {
        lr += ls;
      }

      // P -> bf16 A-fragments
      bf16x8 pa[4];
#pragma unroll
      for (int kb = 0; kb < 2; ++kb) {
        unsigned pk[8], ex[8];
#pragma unroll
        for (int i2 = 0; i2 < 8; ++i2)
          pk[i2] = cvt_pk_bf16(pv[kb][2 * i2], pv[kb][2 * i2 + 1]);
#pragma unroll
        for (int i2 = 0; i2 < 8; ++i2)
          ex[i2] = (unsigned)__shfl_xor((int)pk[i2], 32);
        union { unsigned u[4]; bf16x8 v8; } f0, f1;
        f0.u[0] = hi ? ex[2] : pk[0];
        f0.u[1] = hi ? ex[3] : pk[1];
        f0.u[2] = hi ? pk[2] : ex[0];
        f0.u[3] = hi ? pk[3] : ex[1];
        f1.u[0] = hi ? ex[6] : pk[4];
        f1.u[1] = hi ? ex[7] : pk[5];
        f1.u[2] = hi ? pk[6] : ex[4];
        f1.u[3] = hi ? pk[7] : ex[5];
        pa[2 * kb]     = f0.v8;
        pa[2 * kb + 1] = f1.v8;
      }

      // O += P V
#pragma unroll
      for (int s = 0; s < 4; ++s) {
        const int g = ((s << 1) | hi) ^ (l31 & 7);
        bf16x8 vf0 = *(const bf16x8*)&Vs[cur][l31 * 64 + 8 * g];
        bf16x8 vf1 = *(const bf16x8*)&Vs[cur][(32 + l31) * 64 + 8 * g];
        oa[0] = __builtin_amdgcn_mfma_f32_32x32x16_bf16(pa[s], vf0, oa[0], 0, 0, 0);
        oa[1] = __builtin_amdgcn_mfma_f32_32x32x16_bf16(pa[s], vf1, oa[1], 0, 0, 0);
      }
    }

    asm volatile("s_waitcnt lgkmcnt(0)" ::: "memory");
    __builtin_amdgcn_s_barrier();
  }

  const float linv = 1.f / lr;
#pragma unroll
  for (int r = 0; r < 16; ++r) {
    const int crow = (r & 3) + 8 * (r >> 2) + 4 * hi;
    const float li = __shfl(linv, crow | (lane & 32));
    const long row = qw + crow;
    og[qbase + row * D + l31]      = f2bf(oa[0][r] * li);
    og[qbase + row * D + 32 + l31] = f2bf(oa[1][r] * li);
  }
}

// ------------------------------- launcher -----------------------------------
extern "C" void kernel_launch(void* const* d_in, const int* in_sizes, int n_in,
                              void* d_out, int out_size, void* d_ws, size_t ws_size,
                              hipStream_t stream) {
  (void)in_sizes; (void)n_in; (void)out_size; (void)ws_size;
  const float* h     = (const float*)d_in[0];
  const float* ln1_g = (const float*)d_in[1];
  const float* ln1_b = (const float*)d_in[2];
  const float* wq    = (const float*)d_in[3];
  const float* bq    = (const float*)d_in[4];
  const float* wk    = (const float*)d_in[5];
  const float* bk    = (const float*)d_in[6];
  const float* wv    = (const float*)d_in[7];
  const float* bv    = (const float*)d_in[8];
  const float* wo    = (const float*)d_in[9];
  const float* bo    = (const float*)d_in[10];
  const float* ln2_g = (const float*)d_in[11];
  const float* ln2_b = (const float*)d_in[12];
  const float* wfc   = (const float*)d_in[13];
  const float* bfc   = (const float*)d_in[14];
  const float* wproj = (const float*)d_in[15];
  const float* bproj = (const float*)d_in[16];

  const int B = 4, S = 2048, D = 1024, H = 16, F = 4096, T = B * S;

  char* ws = (char*)d_ws;
  size_t off = 0;
  auto alloc = [&](size_t bytes) {
    void* p = ws + off;
    off += (bytes + 255) & ~(size_t)255;
    return p;
  };
  short* xb  = (short*)alloc((size_t)T * D * 2);
  short* qb  = (short*)alloc((size_t)T * D * 2);
  short* kb  = (short*)alloc((size_t)T * D * 2);
  short* vb  = (short*)alloc((size_t)T * D * 2);
  short* ob  = (short*)alloc((size_t)T * D * 2);
  float* h2  = (float*)alloc((size_t)T * D * 4);
  short* wqb = (short*)alloc((size_t)D * D * 2);
  short* wkb = (short*)alloc((size_t)D * D * 2);
  short* wvb = (short*)alloc((size_t)D * D * 2);
  short* wob = (short*)alloc((size_t)D * D * 2);
  short* wfcb   = (short*)alloc((size_t)F * D * 2);
  short* wprojb = (short*)alloc((size_t)D * F * 2);
  short* ub  = qb;            // u [T,F] aliases q/k/v/o (dead by FC time)
  short* vtg = (short*)h2;    // V^T aliases h2 (dead before Wo writes h2)

  cvt_f32_bf16<<<dim3(D * D / 4 / 256), 256, 0, stream>>>(wq, wqb, D * D / 4);
  cvt_f32_bf16<<<dim3(D * D / 4 / 256), 256, 0, stream>>>(wk, wkb, D * D / 4);
  cvt_f32_bf16<<<dim3(D * D / 4 / 256), 256, 0, stream>>>(wv, wvb, D * D / 4);
  cvt_f32_bf16<<<dim3(D * D / 4 / 256), 256, 0, stream>>>(wo, wob, D * D / 4);
  cvt_f32_bf16<<<dim3(F * D / 4 / 256), 256, 0, stream>>>(wfc, wfcb, F * D / 4);
  cvt_f32_bf16<<<dim3(D * F / 4 / 256), 256, 0, stream>>>(wproj, wprojb, D * F / 4);

  // attention sub-block
  ln_fwd<<<dim3(T), 256, 0, stream>>>(h, ln1_g, ln1_b, xb);
  gemm_bt<1, 0, 0><<<dim3(D / 128, T / 128), 256, 0, stream>>>(xb, wqb, bq, nullptr, qb, T, D, D);
  gemm_bt<1, 0, 0><<<dim3(D / 128, T / 128), 256, 0, stream>>>(xb, wkb, bk, nullptr, kb, T, D, D);
  gemm_bt<1, 0, 0><<<dim3(D / 128, T / 128), 256, 0, stream>>>(xb, wvb, bv, nullptr, vb, T, D, D);
  transpose_v<<<dim3(S / 64, B * H), 256, 0, stream>>>(vb, vtg, S, D, H);
  attn_fwd2<<<dim3(S / 128, B * H), 256, 0, stream>>>(qb, kb, vtg, ob, S, D, H);
  gemm_bt<0, 1, 0><<<dim3(D / 128, T / 128), 256, 0, stream>>>(ob, wob, bo, h, h2, T, D, D);

  // MLP sub-block
  ln_fwd<<<dim3(T), 256, 0, stream>>>(h2, ln2_g, ln2_b, xb);
  gemm_bt256<1, 0, 1><<<dim3(F / 256, T / 256), 512, 0, stream>>>(xb, wfcb, bfc, nullptr, ub, T, F, D);
  gemm_bt<0, 1, 0><<<dim3(D / 128, T / 128), 256, 0, stream>>>(ub, wprojb, bproj, h2, (float*)d_out, T, D, F);
}

// Round 5
// 432.620 us; speedup vs baseline: 1.5309x; 1.0963x over previous
//
#include <hip/hip_runtime.h>
#include <hip/hip_bf16.h>
#include <stdint.h>

// ---------------------------------------------------------------------------
// GPT-2 block on MI355X (gfx950). Round 5:
//  - QKV fused into one GEMM (concat weights/bias), all GEMMs on a new
//    128x256-tile dbuf kernel (8 waves, counted vmcnt(6), granule XOR swizzle,
//    setprio, XCD swizzle) whose grid >= 256 blocks for every shape here.
//  - attn: causal load balance via q-tile pairing (block i does tiles 15-i
//    and i => uniform 36 tiles/block), exp2-based softmax (log2e folded into
//    the QK scale).
// ---------------------------------------------------------------------------

typedef short bf16x8 __attribute__((ext_vector_type(8)));
typedef float f32x4  __attribute__((ext_vector_type(4)));
typedef float f32x16 __attribute__((ext_vector_type(16)));
typedef short s16x4  __attribute__((ext_vector_type(4)));

__device__ __forceinline__ short f2bf(float f) {
  union { float f; uint32_t u; } a;
  a.f = f;
  uint32_t r = a.u + 0x7fffu + ((a.u >> 16) & 1u);  // RNE
  return (short)(r >> 16);
}

__device__ __forceinline__ unsigned cvt_pk_bf16(float lo, float hi_) {
  unsigned r;
  asm("v_cvt_pk_bf16_f32 %0, %1, %2" : "=v"(r) : "v"(lo), "v"(hi_));
  return r;
}

__device__ __forceinline__ void gload_lds16(const void* g, void* l) {
  __builtin_amdgcn_global_load_lds(
      (const __attribute__((address_space(1))) void*)g,
      (__attribute__((address_space(3))) void*)l, 16, 0, 0);
}

__device__ __forceinline__ float gelu_f(float x) {
  float y = 0.7978845608028654f * (x + 0.044715f * x * x * x);
  y = fminf(fmaxf(y, -20.f), 20.f);
  float e = __expf(2.f * y);
  return 0.5f * x * (1.f + (e - 1.f) / (e + 1.f));  // tanh via exp
}

// --------------------------- weight fp32 -> bf16 ---------------------------
__global__ __launch_bounds__(256)
void cvt_f32_bf16(const float* __restrict__ in, short* __restrict__ out, int n4) {
  int i = blockIdx.x * 256 + threadIdx.x;
  if (i < n4) {
    float4 v = ((const float4*)in)[i];
    s16x4 o;
    o[0] = f2bf(v.x); o[1] = f2bf(v.y); o[2] = f2bf(v.z); o[3] = f2bf(v.w);
    ((s16x4*)out)[i] = o;
  }
}

// ------------------------------- LayerNorm ---------------------------------
__global__ __launch_bounds__(256)
void ln_fwd(const float* __restrict__ x, const float* __restrict__ g,
            const float* __restrict__ b, short* __restrict__ y) {
  const long row = blockIdx.x;
  const int t = threadIdx.x;
  const float4 xv = ((const float4*)(x + row * 1024))[t];
  float s  = xv.x + xv.y + xv.z + xv.w;
  float ss = xv.x * xv.x + xv.y * xv.y + xv.z * xv.z + xv.w * xv.w;
#pragma unroll
  for (int m = 1; m < 64; m <<= 1) {
    s  += __shfl_xor(s, m);
    ss += __shfl_xor(ss, m);
  }
  __shared__ float rs[4], rss[4];
  const int wid = t >> 6, lane = t & 63;
  if (lane == 0) { rs[wid] = s; rss[wid] = ss; }
  __syncthreads();
  s  = rs[0] + rs[1] + rs[2] + rs[3];
  ss = rss[0] + rss[1] + rss[2] + rss[3];
  const float mu   = s * (1.f / 1024.f);
  const float var  = ss * (1.f / 1024.f) - mu * mu;
  const float rstd = rsqrtf(var + 1e-5f);
  const float4 gv = ((const float4*)g)[t];
  const float4 bv = ((const float4*)b)[t];
  s16x4 ov;
  ov[0] = f2bf((xv.x - mu) * rstd * gv.x + bv.x);
  ov[1] = f2bf((xv.y - mu) * rstd * gv.y + bv.y);
  ov[2] = f2bf((xv.z - mu) * rstd * gv.z + bv.z);
  ov[3] = f2bf((xv.w - mu) * rstd * gv.w + bv.w);
  *(s16x4*)(y + row * 1024 + t * 4) = ov;
}

// ------------------------- GEMM 128x256 (NT, dbuf) ---------------------------
// C[M,N] = A[M,K](bf16) . W[N,K](bf16)^T + bias (+res) (+gelu)
// 512 threads, 8 waves (2M x 4N), per-wave 64x64 (4x4 frags), BK=64.
// Dbuf LDS 96KB, granule XOR swizzle (slot g of row r holds global granule
// g^(r&7); staged via swizzled global source, linear LDS dest).
// Counted vmcnt(6): next tile's 6 loads/thread stay in flight across K-step.
// 1-D grid (nwg = (M/128)*(N/256) blocks), XCD-aware swizzle when nwg%8==0.
template <int OUT_BF16, int HAS_RES, int HAS_GELU>
__global__ __launch_bounds__(512, 2)
void gemm_bt2(const short* __restrict__ A, const short* __restrict__ W,
              const float* __restrict__ bias, const float* __restrict__ res,
              void* __restrict__ out, int M, int N, int K) {
  __shared__ short As[2][128 * 64];
  __shared__ short Bs[2][256 * 64];
  const int tid = threadIdx.x;
  const int wid = tid >> 6, lane = tid & 63;
  const int l16 = lane & 15, lg = lane >> 4;
  const int wm = wid >> 2, wn = wid & 3;     // 2 x 4 wave grid

  const int nbx = N >> 8;
  const int nwg = nbx * (M >> 7);
  int flat = (int)blockIdx.x;
  if ((nwg & 7) == 0) flat = (flat & 7) * (nwg >> 3) + (flat >> 3);
  const int brow = (flat / nbx) * 128, bcol = (flat % nbx) * 256;

  f32x4 acc[4][4] = {};

  const int r0 = tid >> 3, g0 = tid & 7;

  auto STAGE = [&](int buf, int kt) {
#pragma unroll
    for (int i = 0; i < 2; ++i) {
      const int row = i * 64 + r0;
      gload_lds16(A + (long)(brow + row) * K + kt + 8 * (g0 ^ (row & 7)),
                  &As[buf][(i * 512 + wid * 64) * 8]);
    }
#pragma unroll
    for (int i = 0; i < 4; ++i) {
      const int row = i * 64 + r0;
      gload_lds16(W + (long)(bcol + row) * K + kt + 8 * (g0 ^ (row & 7)),
                  &Bs[buf][(i * 512 + wid * 64) * 8]);
    }
  };

  const int NT = K >> 6;
  STAGE(0, 0);
  STAGE(1, 64);

  for (int t = 0; t < NT; ++t) {
    const int cur = t & 1;
    if (t < NT - 1) asm volatile("s_waitcnt vmcnt(6)" ::: "memory");
    else            asm volatile("s_waitcnt vmcnt(0)" ::: "memory");
    __builtin_amdgcn_s_barrier();

    bf16x8 af0[4], af1[4], bf0[4], bf1[4];
#pragma unroll
    for (int m = 0; m < 4; ++m) {
      const int r = wm * 64 + m * 16 + l16;
      af0[m] = *(const bf16x8*)&As[cur][r * 64 + 8 * (lg ^ (r & 7))];
      af1[m] = *(const bf16x8*)&As[cur][r * 64 + 8 * ((4 + lg) ^ (r & 7))];
    }
#pragma unroll
    for (int n = 0; n < 4; ++n) {
      const int r = wn * 64 + n * 16 + l16;
      bf0[n] = *(const bf16x8*)&Bs[cur][r * 64 + 8 * (lg ^ (r & 7))];
      bf1[n] = *(const bf16x8*)&Bs[cur][r * 64 + 8 * ((4 + lg) ^ (r & 7))];
    }

    __builtin_amdgcn_s_setprio(1);
#pragma unroll
    for (int m = 0; m < 4; ++m)
#pragma unroll
      for (int n = 0; n < 4; ++n)
        acc[m][n] = __builtin_amdgcn_mfma_f32_16x16x32_bf16(af0[m], bf0[n], acc[m][n], 0, 0, 0);
    __builtin_amdgcn_s_setprio(0);

    asm volatile("s_waitcnt lgkmcnt(0)" ::: "memory");
    __builtin_amdgcn_s_barrier();
    if (t + 2 < NT) STAGE(cur, (t + 2) * 64);

    __builtin_amdgcn_s_setprio(1);
#pragma unroll
    for (int m = 0; m < 4; ++m)
#pragma unroll
      for (int n = 0; n < 4; ++n)
        acc[m][n] = __builtin_amdgcn_mfma_f32_16x16x32_bf16(af1[m], bf1[n], acc[m][n], 0, 0, 0);
    __builtin_amdgcn_s_setprio(0);
  }

#pragma unroll
  for (int n = 0; n < 4; ++n) {
    const int col = bcol + wn * 64 + n * 16 + l16;
    const float bb = bias[col];
#pragma unroll
    for (int m = 0; m < 4; ++m) {
#pragma unroll
      for (int j = 0; j < 4; ++j) {
        const long row = brow + wm * 64 + m * 16 + lg * 4 + j;
        float vv = acc[m][n][j] + bb;
        if (HAS_GELU) vv = gelu_f(vv);
        if (HAS_RES) vv += res[row * N + col];
        if (OUT_BF16) ((short*)out)[row * N + col] = f2bf(vv);
        else          ((float*)out)[row * N + col] = vv;
      }
    }
  }
}

// ------------------------- V transpose (per head) ---------------------------
// v (row stride ldv, head cols at hh*64) -> vtg [(b*H+h)*64 + dh][S]
__global__ __launch_bounds__(256)
void transpose_v(const short* __restrict__ v, short* __restrict__ vtg,
                 int S, int ldv, int H) {
  __shared__ short t[64][66];
  const int bh = blockIdx.y, b = bh / H, hh = bh % H;
  const int s0 = blockIdx.x * 64;
  const int tid = threadIdx.x;
#pragma unroll
  for (int i = 0; i < 2; ++i) {
    const int c = i * 256 + tid;
    const int sl = c >> 3, d8 = (c & 7) * 8;
    bf16x8 vv = *(const bf16x8*)&v[((long)b * S + s0 + sl) * ldv + hh * 64 + d8];
#pragma unroll
    for (int j = 0; j < 8; ++j) t[d8 + j][sl] = vv[j];
  }
  __syncthreads();
#pragma unroll
  for (int i = 0; i < 2; ++i) {
    const int c = i * 256 + tid;
    const int dl = c >> 3, s8 = (c & 7) * 8;
    bf16x8 ov;
#pragma unroll
    for (int j = 0; j < 8; ++j) ov[j] = t[dl][s8 + j];
    *(bf16x8*)&vtg[((long)bh * 64 + dl) * S + s0 + s8] = ov;
  }
}

// --------------------------- causal flash attention -------------------------
// Swapped QK^T in-register softmax; dbuf K/V with counted vmcnt; q-tile
// PAIRING for causal load balance: block pr handles q-tiles (15-pr, pr) =>
// uniform 36 K/V-tiles per block. exp2-based softmax (log2e in QK scale).
__global__ __launch_bounds__(256, 4)
void attn_fwd2(const short* __restrict__ qg, const short* __restrict__ kg,
               const short* __restrict__ vtg, short* __restrict__ og,
               int S, int ldq, int D, int H) {
  const int tid = threadIdx.x, wid = tid >> 6, lane = tid & 63;
  const int l31 = lane & 31, hi = lane >> 5;
  const int bh = blockIdx.y;
  const int b = bh / H, hh = bh % H;
  const int pr = blockIdx.x;          // 0..(S/256-1)
  const int nqt = S >> 7;             // q-tiles of 128
  const long qbase = (long)b * S * ldq + hh * 64;   // q/k base (stride ldq)
  const long obase = (long)b * S * D + hh * 64;     // o base (stride D)
  const long vbase = (long)bh * 64 * S;

  __shared__ short Ks[2][64 * 64];
  __shared__ short Vs[2][64 * 64];

  auto STAGE = [&](int buf, int k0) {
#pragma unroll
    for (int i = 0; i < 2; ++i) {
      const int c = i * 256 + tid;
      const int row = c >> 3, gl = c & 7;
      gload_lds16(&kg[qbase + (long)(k0 + row) * ldq + 8 * (gl ^ (row & 7))],
                  &Ks[buf][(i * 256 + wid * 64) * 8]);
      gload_lds16(&vtg[vbase + (long)row * S + k0 + 8 * (gl ^ (row & 7))],
                  &Vs[buf][(i * 256 + wid * 64) * 8]);
    }
  };

  const float kScale = 0.125f * 1.44269504089f;  // 1/sqrt(64) * log2(e)

  for (int half = 0; half < 2; ++half) {
    const int qt = half ? pr : (nqt - 1 - pr);   // long q-block first
    const int q0 = qt * 128;
    const int qw = q0 + wid * 32;
    const int qv = qw + l31;

    bf16x8 qf[4];
#pragma unroll
    for (int s = 0; s < 4; ++s)
      qf[s] = *(const bf16x8*)&qg[qbase + (long)qv * ldq + 16 * s + 8 * hi];

    f32x16 oa[2] = {};
    float mr = -3000.f, lr = 0.f;

    const int ntiles = qt * 2 + 2;

    STAGE(0, 0);
    for (int t = 0; t < ntiles; ++t) {
      const int cur = t & 1;
      const int k0 = t * 64;
      if (t + 1 < ntiles) {
        STAGE(cur ^ 1, k0 + 64);
        asm volatile("s_waitcnt vmcnt(4)" ::: "memory");
      } else {
        asm volatile("s_waitcnt vmcnt(0)" ::: "memory");
      }
      __builtin_amdgcn_s_barrier();

      if (k0 < qw + 32) {   // tile not fully masked for this wave
        f32x16 st[2] = {};
#pragma unroll
        for (int s = 0; s < 4; ++s) {
          const int g = ((s << 1) | hi) ^ (l31 & 7);
          bf16x8 kf0 = *(const bf16x8*)&Ks[cur][l31 * 64 + 8 * g];
          bf16x8 kf1 = *(const bf16x8*)&Ks[cur][(32 + l31) * 64 + 8 * g];
          st[0] = __builtin_amdgcn_mfma_f32_32x32x16_bf16(kf0, qf[s], st[0], 0, 0, 0);
          st[1] = __builtin_amdgcn_mfma_f32_32x32x16_bf16(kf1, qf[s], st[1], 0, 0, 0);
        }

        const bool need_mask = (k0 + 63 > qw);
        float pv[2][16];
#pragma unroll
        for (int kb = 0; kb < 2; ++kb)
#pragma unroll
          for (int r = 0; r < 16; ++r) {
            float v = st[kb][r] * kScale;
            if (need_mask) {
              const int key = k0 + kb * 32 + (r & 3) + 8 * (r >> 2) + 4 * hi;
              if (key > qv) v = -1e30f;
            }
            pv[kb][r] = v;
          }

        float t8[8];
#pragma unroll
        for (int j = 0; j < 8; ++j)
          t8[j] = fmaxf(fmaxf(pv[0][j], pv[0][8 + j]), fmaxf(pv[1][j], pv[1][8 + j]));
        float rm = fmaxf(fmaxf(fmaxf(t8[0], t8[1]), fmaxf(t8[2], t8[3])),
                         fmaxf(fmaxf(t8[4], t8[5]), fmaxf(t8[6], t8[7])));
        rm = fmaxf(rm, __shfl_xor(rm, 32));

        const bool defer = (bool)__all(rm <= mr + 8.f);
        const float mn = defer ? mr : fmaxf(mr, rm);

        float a0 = 0.f, a1 = 0.f, a2 = 0.f, a3 = 0.f;
#pragma unroll
        for (int r = 0; r < 8; ++r) {
          float p0 = exp2f(pv[0][r] - mn);      pv[0][r] = p0;      a0 += p0;
          float p1 = exp2f(pv[0][8 + r] - mn);  pv[0][8 + r] = p1;  a1 += p1;
          float p2 = exp2f(pv[1][r] - mn);      pv[1][r] = p2;      a2 += p2;
          float p3 = exp2f(pv[1][8 + r] - mn);  pv[1][8 + r] = p3;  a3 += p3;
        }
        float ls = (a0 + a1) + (a2 + a3);
        ls += __shfl_xor(ls, 32);

        if (!defer) {
          const float alpha = exp2f(mr - mn);
          lr = lr * alpha + ls;
          mr = mn;
#pragma unroll
          for (int r = 0; r < 16; ++r) {
            const int crow = (r & 3) + 8 * (r >> 2) + 4 * hi;
            const float ar = __shfl(alpha, crow | (lane & 32));
            oa[0][r] *= ar;
            oa[1][r] *= ar;
          }
        } else {
          lr += ls;
        }

        bf16x8 pa[4];
#pragma unroll
        for (int kb = 0; kb < 2; ++kb) {
          unsigned pk[8], ex[8];
#pragma unroll
          for (int i2 = 0; i2 < 8; ++i2)
            pk[i2] = cvt_pk_bf16(pv[kb][2 * i2], pv[kb][2 * i2 + 1]);
#pragma unroll
          for (int i2 = 0; i2 < 8; ++i2)
            ex[i2] = (unsigned)__shfl_xor((int)pk[i2], 32);
          union { unsigned u[4]; bf16x8 v8; } f0, f1;
          f0.u[0] = hi ? ex[2] : pk[0];
          f0.u[1] = hi ? ex[3] : pk[1];
          f0.u[2] = hi ? pk[2] : ex[0];
          f0.u[3] = hi ? pk[3] : ex[1];
          f1.u[0] = hi ? ex[6] : pk[4];
          f1.u[1] = hi ? ex[7] : pk[5];
          f1.u[2] = hi ? pk[6] : ex[4];
          f1.u[3] = hi ? pk[7] : ex[5];
          pa[2 * kb]     = f0.v8;
          pa[2 * kb + 1] = f1.v8;
        }

#pragma unroll
        for (int s = 0; s < 4; ++s) {
          const int g = ((s << 1) | hi) ^ (l31 & 7);
          bf16x8 vf0 = *(const bf16x8*)&Vs[cur][l31 * 64 + 8 * g];
          bf16x8 vf1 = *(const bf16x8*)&Vs[cur][(32 + l31) * 64 + 8 * g];
          oa[0] = __builtin_amdgcn_mfma_f32_32x32x16_bf16(pa[s], vf0, oa[0], 0, 0, 0);
          oa[1] = __builtin_amdgcn_mfma_f32_32x32x16_bf16(pa[s], vf1, oa[1], 0, 0, 0);
        }
      }

      asm volatile("s_waitcnt lgkmcnt(0)" ::: "memory");
      __builtin_amdgcn_s_barrier();
    }

    const float linv = 1.f / lr;
#pragma unroll
    for (int r = 0; r < 16; ++r) {
      const int crow = (r & 3) + 8 * (r >> 2) + 4 * hi;
      const float li = __shfl(linv, crow | (lane & 32));
      const long row = qw + crow;
      og[obase + row * D + l31]      = f2bf(oa[0][r] * li);
      og[obase + row * D + 32 + l31] = f2bf(oa[1][r] * li);
    }
  }
}

// ------------------------------- launcher -----------------------------------
extern "C" void kernel_launch(void* const* d_in, const int* in_sizes, int n_in,
                              void* d_out, int out_size, void* d_ws, size_t ws_size,
                              hipStream_t stream) {
  (void)in_sizes; (void)n_in; (void)out_size; (void)ws_size;
  const float* h     = (const float*)d_in[0];
  const float* ln1_g = (const float*)d_in[1];
  const float* ln1_b = (const float*)d_in[2];
  const float* wq    = (const float*)d_in[3];
  const float* bq    = (const float*)d_in[4];
  const float* wk    = (const float*)d_in[5];
  const float* bk    = (const float*)d_in[6];
  const float* wv    = (const float*)d_in[7];
  const float* bv    = (const float*)d_in[8];
  const float* wo    = (const float*)d_in[9];
  const float* bo    = (const float*)d_in[10];
  const float* ln2_g = (const float*)d_in[11];
  const float* ln2_b = (const float*)d_in[12];
  const float* wfc   = (const float*)d_in[13];
  const float* bfc   = (const float*)d_in[14];
  const float* wproj = (const float*)d_in[15];
  const float* bproj = (const float*)d_in[16];

  const int B = 4, S = 2048, D = 1024, H = 16, F = 4096, T = B * S;
  const int D3 = 3 * D;

  char* ws = (char*)d_ws;
  size_t off = 0;
  auto alloc = [&](size_t bytes) {
    void* p = ws + off;
    off += (bytes + 255) & ~(size_t)255;
    return p;
  };
  short* xb   = (short*)alloc((size_t)T * D * 2);     // ln1(x) / ln2(x)
  short* qkv  = (short*)alloc((size_t)T * D3 * 2);    // fused QKV out [T,3D]
  short* ob   = (short*)alloc((size_t)T * D * 2);     // attn out
  float* h2   = (float*)alloc((size_t)T * D * 4);     // post-attn residual
  short* wqkvb  = (short*)alloc((size_t)D3 * D * 2);
  short* wob    = (short*)alloc((size_t)D * D * 2);
  short* wfcb   = (short*)alloc((size_t)F * D * 2);
  short* wprojb = (short*)alloc((size_t)D * F * 2);
  float* bqkv   = (float*)alloc((size_t)D3 * 4);
  short* ub  = qkv;           // u [T,F]=64MB aliases qkv(48MB)+ob(16MB), dead by FC
  short* vtg = (short*)h2;    // V^T [B*H*64, S] aliases h2 (dead before Wo writes h2)

  // concatenated QKV weights (rows: q then k then v) and bias
  cvt_f32_bf16<<<dim3(D * D / 4 / 256), 256, 0, stream>>>(wq, wqkvb, D * D / 4);
  cvt_f32_bf16<<<dim3(D * D / 4 / 256), 256, 0, stream>>>(wk, wqkvb + (size_t)D * D, D * D / 4);
  cvt_f32_bf16<<<dim3(D * D / 4 / 256), 256, 0, stream>>>(wv, wqkvb + (size_t)2 * D * D, D * D / 4);
  cvt_f32_bf16<<<dim3(D * D / 4 / 256), 256, 0, stream>>>(wo, wob, D * D / 4);
  cvt_f32_bf16<<<dim3(F * D / 4 / 256), 256, 0, stream>>>(wfc, wfcb, F * D / 4);
  cvt_f32_bf16<<<dim3(D * F / 4 / 256), 256, 0, stream>>>(wproj, wprojb, D * F / 4);
  hipMemcpyAsync(bqkv,            bq, D * 4, hipMemcpyDeviceToDevice, stream);
  hipMemcpyAsync(bqkv + D,        bk, D * 4, hipMemcpyDeviceToDevice, stream);
  hipMemcpyAsync(bqkv + 2 * D,    bv, D * 4, hipMemcpyDeviceToDevice, stream);

  // attention sub-block
  ln_fwd<<<dim3(T), 256, 0, stream>>>(h, ln1_g, ln1_b, xb);
  gemm_bt2<1, 0, 0><<<dim3((T / 128) * (D3 / 256)), 512, 0, stream>>>(
      xb, wqkvb, bqkv, nullptr, qkv, T, D3, D);
  transpose_v<<<dim3(S / 64, B * H), 256, 0, stream>>>(qkv + 2 * D, vtg, S, D3, H);
  attn_fwd2<<<dim3(S / 256, B * H), 256, 0, stream>>>(qkv, qkv + D, vtg, ob, S, D3, D, H);
  gemm_bt2<0, 1, 0><<<dim3((T / 128) * (D / 256)), 512, 0, stream>>>(
      ob, wob, bo, h, h2, T, D, D);

  // MLP sub-block
  ln_fwd<<<dim3(T), 256, 0, stream>>>(h2, ln2_g, ln2_b, xb);
  gemm_bt2<1, 0, 1><<<dim3((T / 128) * (F / 256)), 512, 0, stream>>>(
      xb, wfcb, bfc, nullptr, ub, T, F, D);
  gemm_bt2<0, 1, 0><<<dim3((T / 128) * (D / 256)), 512, 0, stream>>>(
      ub, wprojb, bproj, h2, (float*)d_out, T, D, F);
}

// Round 6
// 415.629 us; speedup vs baseline: 1.5935x; 1.0409x over previous
//
#include <hip/hip_runtime.h>
#include <hip/hip_bf16.h>
#include <stdint.h>

// ---------------------------------------------------------------------------
// GPT-2 block on MI355X (gfx950). Round 6:
//  - attn: one 128-row q-tile per block (grid 1024 = 4 blocks/CU, all
//    co-resident) with a placement-aware qt permutation that balances causal
//    work across CUs under XCD round-robin dispatch (stride-256 co-residency)
//    AND consecutive-fill. Doubles occupancy vs round-5 pairing.
//  - GEMMs/LN/transpose unchanged (128x256 dbuf gemm_bt2, fused QKV).
// ---------------------------------------------------------------------------

typedef short bf16x8 __attribute__((ext_vector_type(8)));
typedef float f32x4  __attribute__((ext_vector_type(4)));
typedef float f32x16 __attribute__((ext_vector_type(16)));
typedef short s16x4  __attribute__((ext_vector_type(4)));

__device__ __forceinline__ short f2bf(float f) {
  union { float f; uint32_t u; } a;
  a.f = f;
  uint32_t r = a.u + 0x7fffu + ((a.u >> 16) & 1u);  // RNE
  return (short)(r >> 16);
}

__device__ __forceinline__ unsigned cvt_pk_bf16(float lo, float hi_) {
  unsigned r;
  asm("v_cvt_pk_bf16_f32 %0, %1, %2" : "=v"(r) : "v"(lo), "v"(hi_));
  return r;
}

__device__ __forceinline__ void gload_lds16(const void* g, void* l) {
  __builtin_amdgcn_global_load_lds(
      (const __attribute__((address_space(1))) void*)g,
      (__attribute__((address_space(3))) void*)l, 16, 0, 0);
}

__device__ __forceinline__ float gelu_f(float x) {
  float y = 0.7978845608028654f * (x + 0.044715f * x * x * x);
  y = fminf(fmaxf(y, -20.f), 20.f);
  float e = __expf(2.f * y);
  return 0.5f * x * (1.f + (e - 1.f) / (e + 1.f));  // tanh via exp
}

// --------------------------- weight fp32 -> bf16 ---------------------------
__global__ __launch_bounds__(256)
void cvt_f32_bf16(const float* __restrict__ in, short* __restrict__ out, int n4) {
  int i = blockIdx.x * 256 + threadIdx.x;
  if (i < n4) {
    float4 v = ((const float4*)in)[i];
    s16x4 o;
    o[0] = f2bf(v.x); o[1] = f2bf(v.y); o[2] = f2bf(v.z); o[3] = f2bf(v.w);
    ((s16x4*)out)[i] = o;
  }
}

// ------------------------------- LayerNorm ---------------------------------
__global__ __launch_bounds__(256)
void ln_fwd(const float* __restrict__ x, const float* __restrict__ g,
            const float* __restrict__ b, short* __restrict__ y) {
  const long row = blockIdx.x;
  const int t = threadIdx.x;
  const float4 xv = ((const float4*)(x + row * 1024))[t];
  float s  = xv.x + xv.y + xv.z + xv.w;
  float ss = xv.x * xv.x + xv.y * xv.y + xv.z * xv.z + xv.w * xv.w;
#pragma unroll
  for (int m = 1; m < 64; m <<= 1) {
    s  += __shfl_xor(s, m);
    ss += __shfl_xor(ss, m);
  }
  __shared__ float rs[4], rss[4];
  const int wid = t >> 6, lane = t & 63;
  if (lane == 0) { rs[wid] = s; rss[wid] = ss; }
  __syncthreads();
  s  = rs[0] + rs[1] + rs[2] + rs[3];
  ss = rss[0] + rss[1] + rss[2] + rss[3];
  const float mu   = s * (1.f / 1024.f);
  const float var  = ss * (1.f / 1024.f) - mu * mu;
  const float rstd = rsqrtf(var + 1e-5f);
  const float4 gv = ((const float4*)g)[t];
  const float4 bv = ((const float4*)b)[t];
  s16x4 ov;
  ov[0] = f2bf((xv.x - mu) * rstd * gv.x + bv.x);
  ov[1] = f2bf((xv.y - mu) * rstd * gv.y + bv.y);
  ov[2] = f2bf((xv.z - mu) * rstd * gv.z + bv.z);
  ov[3] = f2bf((xv.w - mu) * rstd * gv.w + bv.w);
  *(s16x4*)(y + row * 1024 + t * 4) = ov;
}

// ------------------------- GEMM 128x256 (NT, dbuf) ---------------------------
template <int OUT_BF16, int HAS_RES, int HAS_GELU>
__global__ __launch_bounds__(512, 2)
void gemm_bt2(const short* __restrict__ A, const short* __restrict__ W,
              const float* __restrict__ bias, const float* __restrict__ res,
              void* __restrict__ out, int M, int N, int K) {
  __shared__ short As[2][128 * 64];
  __shared__ short Bs[2][256 * 64];
  const int tid = threadIdx.x;
  const int wid = tid >> 6, lane = tid & 63;
  const int l16 = lane & 15, lg = lane >> 4;
  const int wm = wid >> 2, wn = wid & 3;     // 2 x 4 wave grid

  const int nbx = N >> 8;
  const int nwg = nbx * (M >> 7);
  int flat = (int)blockIdx.x;
  if ((nwg & 7) == 0) flat = (flat & 7) * (nwg >> 3) + (flat >> 3);
  const int brow = (flat / nbx) * 128, bcol = (flat % nbx) * 256;

  f32x4 acc[4][4] = {};

  const int r0 = tid >> 3, g0 = tid & 7;

  auto STAGE = [&](int buf, int kt) {
#pragma unroll
    for (int i = 0; i < 2; ++i) {
      const int row = i * 64 + r0;
      gload_lds16(A + (long)(brow + row) * K + kt + 8 * (g0 ^ (row & 7)),
                  &As[buf][(i * 512 + wid * 64) * 8]);
    }
#pragma unroll
    for (int i = 0; i < 4; ++i) {
      const int row = i * 64 + r0;
      gload_lds16(W + (long)(bcol + row) * K + kt + 8 * (g0 ^ (row & 7)),
                  &Bs[buf][(i * 512 + wid * 64) * 8]);
    }
  };

  const int NT = K >> 6;
  STAGE(0, 0);
  STAGE(1, 64);

  for (int t = 0; t < NT; ++t) {
    const int cur = t & 1;
    if (t < NT - 1) asm volatile("s_waitcnt vmcnt(6)" ::: "memory");
    else            asm volatile("s_waitcnt vmcnt(0)" ::: "memory");
    __builtin_amdgcn_s_barrier();

    bf16x8 af0[4], af1[4], bf0[4], bf1[4];
#pragma unroll
    for (int m = 0; m < 4; ++m) {
      const int r = wm * 64 + m * 16 + l16;
      af0[m] = *(const bf16x8*)&As[cur][r * 64 + 8 * (lg ^ (r & 7))];
      af1[m] = *(const bf16x8*)&As[cur][r * 64 + 8 * ((4 + lg) ^ (r & 7))];
    }
#pragma unroll
    for (int n = 0; n < 4; ++n) {
      const int r = wn * 64 + n * 16 + l16;
      bf0[n] = *(const bf16x8*)&Bs[cur][r * 64 + 8 * (lg ^ (r & 7))];
      bf1[n] = *(const bf16x8*)&Bs[cur][r * 64 + 8 * ((4 + lg) ^ (r & 7))];
    }

    __builtin_amdgcn_s_setprio(1);
#pragma unroll
    for (int m = 0; m < 4; ++m)
#pragma unroll
      for (int n = 0; n < 4; ++n)
        acc[m][n] = __builtin_amdgcn_mfma_f32_16x16x32_bf16(af0[m], bf0[n], acc[m][n], 0, 0, 0);
    __builtin_amdgcn_s_setprio(0);

    asm volatile("s_waitcnt lgkmcnt(0)" ::: "memory");
    __builtin_amdgcn_s_barrier();
    if (t + 2 < NT) STAGE(cur, (t + 2) * 64);

    __builtin_amdgcn_s_setprio(1);
#pragma unroll
    for (int m = 0; m < 4; ++m)
#pragma unroll
      for (int n = 0; n < 4; ++n)
        acc[m][n] = __builtin_amdgcn_mfma_f32_16x16x32_bf16(af1[m], bf1[n], acc[m][n], 0, 0, 0);
    __builtin_amdgcn_s_setprio(0);
  }

#pragma unroll
  for (int n = 0; n < 4; ++n) {
    const int col = bcol + wn * 64 + n * 16 + l16;
    const float bb = bias[col];
#pragma unroll
    for (int m = 0; m < 4; ++m) {
#pragma unroll
      for (int j = 0; j < 4; ++j) {
        const long row = brow + wm * 64 + m * 16 + lg * 4 + j;
        float vv = acc[m][n][j] + bb;
        if (HAS_GELU) vv = gelu_f(vv);
        if (HAS_RES) vv += res[row * N + col];
        if (OUT_BF16) ((short*)out)[row * N + col] = f2bf(vv);
        else          ((float*)out)[row * N + col] = vv;
      }
    }
  }
}

// ------------------------- V transpose (per head) ---------------------------
__global__ __launch_bounds__(256)
void transpose_v(const short* __restrict__ v, short* __restrict__ vtg,
                 int S, int ldv, int H) {
  __shared__ short t[64][66];
  const int bh = blockIdx.y, b = bh / H, hh = bh % H;
  const int s0 = blockIdx.x * 64;
  const int tid = threadIdx.x;
#pragma unroll
  for (int i = 0; i < 2; ++i) {
    const int c = i * 256 + tid;
    const int sl = c >> 3, d8 = (c & 7) * 8;
    bf16x8 vv = *(const bf16x8*)&v[((long)b * S + s0 + sl) * ldv + hh * 64 + d8];
#pragma unroll
    for (int j = 0; j < 8; ++j) t[d8 + j][sl] = vv[j];
  }
  __syncthreads();
#pragma unroll
  for (int i = 0; i < 2; ++i) {
    const int c = i * 256 + tid;
    const int dl = c >> 3, s8 = (c & 7) * 8;
    bf16x8 ov;
#pragma unroll
    for (int j = 0; j < 8; ++j) ov[j] = t[dl][s8 + j];
    *(bf16x8*)&vtg[((long)bh * 64 + dl) * S + s0 + s8] = ov;
  }
}

// --------------------------- causal flash attention -------------------------
// One 128-row q-tile per block; grid = nqt*BH = 1024 (all co-resident,
// 4 blocks/CU). qt chosen via a permutation balanced for BOTH stride-256
// co-residency (XCD round-robin) and consecutive fill, so each CU's 4
// resident blocks sum to ~uniform causal work.
__global__ __launch_bounds__(256, 4)
void attn_fwd2(const short* __restrict__ qg, const short* __restrict__ kg,
               const short* __restrict__ vtg, short* __restrict__ og,
               int S, int ldq, int D, int H) {
  const int tid = threadIdx.x, wid = tid >> 6, lane = tid & 63;
  const int l31 = lane & 31, hi = lane >> 5;
  const int fid = blockIdx.x;
  const int bh = fid & 63;
  const int b = bh / H, hh = bh % H;
  // perm: consecutive quads sum 30; stride-4 classes sum 32/28/28/32
  static const int perm[16] = {15, 0, 8, 7, 1, 14, 6, 9, 13, 2, 10, 5, 3, 12, 4, 11};
  const int qt = perm[(fid >> 6) & 15];
  const int q0 = qt * 128;
  const long qbase = (long)b * S * ldq + hh * 64;   // q/k base (stride ldq)
  const long obase = (long)b * S * D + hh * 64;     // o base (stride D)
  const long vbase = (long)bh * 64 * S;

  __shared__ short Ks[2][64 * 64];
  __shared__ short Vs[2][64 * 64];

  auto STAGE = [&](int buf, int k0) {
#pragma unroll
    for (int i = 0; i < 2; ++i) {
      const int c = i * 256 + tid;
      const int row = c >> 3, gl = c & 7;
      gload_lds16(&kg[qbase + (long)(k0 + row) * ldq + 8 * (gl ^ (row & 7))],
                  &Ks[buf][(i * 256 + wid * 64) * 8]);
      gload_lds16(&vtg[vbase + (long)row * S + k0 + 8 * (gl ^ (row & 7))],
                  &Vs[buf][(i * 256 + wid * 64) * 8]);
    }
  };

  const float kScale = 0.125f * 1.44269504089f;  // 1/sqrt(64) * log2(e)

  const int qw = q0 + wid * 32;
  const int qv = qw + l31;

  bf16x8 qf[4];
#pragma unroll
  for (int s = 0; s < 4; ++s)
    qf[s] = *(const bf16x8*)&qg[qbase + (long)qv * ldq + 16 * s + 8 * hi];

  f32x16 oa[2] = {};
  float mr = -3000.f, lr = 0.f;

  const int ntiles = qt * 2 + 2;

  STAGE(0, 0);
  for (int t = 0; t < ntiles; ++t) {
    const int cur = t & 1;
    const int k0 = t * 64;
    if (t + 1 < ntiles) {
      STAGE(cur ^ 1, k0 + 64);
      asm volatile("s_waitcnt vmcnt(4)" ::: "memory");
    } else {
      asm volatile("s_waitcnt vmcnt(0)" ::: "memory");
    }
    __builtin_amdgcn_s_barrier();

    if (k0 < qw + 32) {   // tile not fully masked for this wave
      f32x16 st[2] = {};
#pragma unroll
      for (int s = 0; s < 4; ++s) {
        const int g = ((s << 1) | hi) ^ (l31 & 7);
        bf16x8 kf0 = *(const bf16x8*)&Ks[cur][l31 * 64 + 8 * g];
        bf16x8 kf1 = *(const bf16x8*)&Ks[cur][(32 + l31) * 64 + 8 * g];
        st[0] = __builtin_amdgcn_mfma_f32_32x32x16_bf16(kf0, qf[s], st[0], 0, 0, 0);
        st[1] = __builtin_amdgcn_mfma_f32_32x32x16_bf16(kf1, qf[s], st[1], 0, 0, 0);
      }

      const bool need_mask = (k0 + 63 > qw);
      float pv[2][16];
#pragma unroll
      for (int kb = 0; kb < 2; ++kb)
#pragma unroll
        for (int r = 0; r < 16; ++r) {
          float v = st[kb][r] * kScale;
          if (need_mask) {
            const int key = k0 + kb * 32 + (r & 3) + 8 * (r >> 2) + 4 * hi;
            if (key > qv) v = -1e30f;
          }
          pv[kb][r] = v;
        }

      float t8[8];
#pragma unroll
      for (int j = 0; j < 8; ++j)
        t8[j] = fmaxf(fmaxf(pv[0][j], pv[0][8 + j]), fmaxf(pv[1][j], pv[1][8 + j]));
      float rm = fmaxf(fmaxf(fmaxf(t8[0], t8[1]), fmaxf(t8[2], t8[3])),
                       fmaxf(fmaxf(t8[4], t8[5]), fmaxf(t8[6], t8[7])));
      rm = fmaxf(rm, __shfl_xor(rm, 32));

      const bool defer = (bool)__all(rm <= mr + 8.f);
      const float mn = defer ? mr : fmaxf(mr, rm);

      float a0 = 0.f, a1 = 0.f, a2 = 0.f, a3 = 0.f;
#pragma unroll
      for (int r = 0; r < 8; ++r) {
        float p0 = exp2f(pv[0][r] - mn);      pv[0][r] = p0;      a0 += p0;
        float p1 = exp2f(pv[0][8 + r] - mn);  pv[0][8 + r] = p1;  a1 += p1;
        float p2 = exp2f(pv[1][r] - mn);      pv[1][r] = p2;      a2 += p2;
        float p3 = exp2f(pv[1][8 + r] - mn);  pv[1][8 + r] = p3;  a3 += p3;
      }
      float ls = (a0 + a1) + (a2 + a3);
      ls += __shfl_xor(ls, 32);

      if (!defer) {
        const float alpha = exp2f(mr - mn);
        lr = lr * alpha + ls;
        mr = mn;
#pragma unroll
        for (int r = 0; r < 16; ++r) {
          const int crow = (r & 3) + 8 * (r >> 2) + 4 * hi;
          const float ar = __shfl(alpha, crow | (lane & 32));
          oa[0][r] *= ar;
          oa[1][r] *= ar;
        }
      } else {
        lr += ls;
      }

      bf16x8 pa[4];
#pragma unroll
      for (int kb = 0; kb < 2; ++kb) {
        unsigned pk[8], ex[8];
#pragma unroll
        for (int i2 = 0; i2 < 8; ++i2)
          pk[i2] = cvt_pk_bf16(pv[kb][2 * i2], pv[kb][2 * i2 + 1]);
#pragma unroll
        for (int i2 = 0; i2 < 8; ++i2)
          ex[i2] = (unsigned)__shfl_xor((int)pk[i2], 32);
        union { unsigned u[4]; bf16x8 v8; } f0, f1;
        f0.u[0] = hi ? ex[2] : pk[0];
        f0.u[1] = hi ? ex[3] : pk[1];
        f0.u[2] = hi ? pk[2] : ex[0];
        f0.u[3] = hi ? pk[3] : ex[1];
        f1.u[0] = hi ? ex[6] : pk[4];
        f1.u[1] = hi ? ex[7] : pk[5];
        f1.u[2] = hi ? pk[6] : ex[4];
        f1.u[3] = hi ? pk[7] : ex[5];
        pa[2 * kb]     = f0.v8;
        pa[2 * kb + 1] = f1.v8;
      }

#pragma unroll
      for (int s = 0; s < 4; ++s) {
        const int g = ((s << 1) | hi) ^ (l31 & 7);
        bf16x8 vf0 = *(const bf16x8*)&Vs[cur][l31 * 64 + 8 * g];
        bf16x8 vf1 = *(const bf16x8*)&Vs[cur][(32 + l31) * 64 + 8 * g];
        oa[0] = __builtin_amdgcn_mfma_f32_32x32x16_bf16(pa[s], vf0, oa[0], 0, 0, 0);
        oa[1] = __builtin_amdgcn_mfma_f32_32x32x16_bf16(pa[s], vf1, oa[1], 0, 0, 0);
      }
    }

    asm volatile("s_waitcnt lgkmcnt(0)" ::: "memory");
    __builtin_amdgcn_s_barrier();
  }

  const float linv = 1.f / lr;
#pragma unroll
  for (int r = 0; r < 16; ++r) {
    const int crow = (r & 3) + 8 * (r >> 2) + 4 * hi;
    const float li = __shfl(linv, crow | (lane & 32));
    const long row = qw + crow;
    og[obase + row * D + l31]      = f2bf(oa[0][r] * li);
    og[obase + row * D + 32 + l31] = f2bf(oa[1][r] * li);
  }
}

// ------------------------------- launcher -----------------------------------
extern "C" void kernel_launch(void* const* d_in, const int* in_sizes, int n_in,
                              void* d_out, int out_size, void* d_ws, size_t ws_size,
                              hipStream_t stream) {
  (void)in_sizes; (void)n_in; (void)out_size; (void)ws_size;
  const float* h     = (const float*)d_in[0];
  const float* ln1_g = (const float*)d_in[1];
  const float* ln1_b = (const float*)d_in[2];
  const float* wq    = (const float*)d_in[3];
  const float* bq    = (const float*)d_in[4];
  const float* wk    = (const float*)d_in[5];
  const float* bk    = (const float*)d_in[6];
  const float* wv    = (const float*)d_in[7];
  const float* bv    = (const float*)d_in[8];
  const float* wo    = (const float*)d_in[9];
  const float* bo    = (const float*)d_in[10];
  const float* ln2_g = (const float*)d_in[11];
  const float* ln2_b = (const float*)d_in[12];
  const float* wfc   = (const float*)d_in[13];
  const float* bfc   = (const float*)d_in[14];
  const float* wproj = (const float*)d_in[15];
  const float* bproj = (const float*)d_in[16];

  const int B = 4, S = 2048, D = 1024, H = 16, F = 4096, T = B * S;
  const int D3 = 3 * D;

  char* ws = (char*)d_ws;
  size_t off = 0;
  auto alloc = [&](size_t bytes) {
    void* p = ws + off;
    off += (bytes + 255) & ~(size_t)255;
    return p;
  };
  short* xb   = (short*)alloc((size_t)T * D * 2);     // ln1(x) / ln2(x)
  short* qkv  = (short*)alloc((size_t)T * D3 * 2);    // fused QKV out [T,3D]
  short* ob   = (short*)alloc((size_t)T * D * 2);     // attn out
  float* h2   = (float*)alloc((size_t)T * D * 4);     // post-attn residual
  short* wqkvb  = (short*)alloc((size_t)D3 * D * 2);
  short* wob    = (short*)alloc((size_t)D * D * 2);
  short* wfcb   = (short*)alloc((size_t)F * D * 2);
  short* wprojb = (short*)alloc((size_t)D * F * 2);
  float* bqkv   = (float*)alloc((size_t)D3 * 4);
  short* ub  = qkv;           // u [T,F]=64MB aliases qkv(48MB)+ob(16MB), dead by FC
  short* vtg = (short*)h2;    // V^T [B*H*64, S] aliases h2 (dead before Wo writes h2)

  // concatenated QKV weights (rows: q then k then v) and bias
  cvt_f32_bf16<<<dim3(D * D / 4 / 256), 256, 0, stream>>>(wq, wqkvb, D * D / 4);
  cvt_f32_bf16<<<dim3(D * D / 4 / 256), 256, 0, stream>>>(wk, wqkvb + (size_t)D * D, D * D / 4);
  cvt_f32_bf16<<<dim3(D * D / 4 / 256), 256, 0, stream>>>(wv, wqkvb + (size_t)2 * D * D, D * D / 4);
  cvt_f32_bf16<<<dim3(D * D / 4 / 256), 256, 0, stream>>>(wo, wob, D * D / 4);
  cvt_f32_bf16<<<dim3(F * D / 4 / 256), 256, 0, stream>>>(wfc, wfcb, F * D / 4);
  cvt_f32_bf16<<<dim3(D * F / 4 / 256), 256, 0, stream>>>(wproj, wprojb, D * F / 4);
  hipMemcpyAsync(bqkv,            bq, D * 4, hipMemcpyDeviceToDevice, stream);
  hipMemcpyAsync(bqkv + D,        bk, D * 4, hipMemcpyDeviceToDevice, stream);
  hipMemcpyAsync(bqkv + 2 * D,    bv, D * 4, hipMemcpyDeviceToDevice, stream);

  // attention sub-block
  ln_fwd<<<dim3(T), 256, 0, stream>>>(h, ln1_g, ln1_b, xb);
  gemm_bt2<1, 0, 0><<<dim3((T / 128) * (D3 / 256)), 512, 0, stream>>>(
      xb, wqkvb, bqkv, nullptr, qkv, T, D3, D);
  transpose_v<<<dim3(S / 64, B * H), 256, 0, stream>>>(qkv + 2 * D, vtg, S, D3, H);
  attn_fwd2<<<dim3((S / 128) * (B * H / 64) * 64), 256, 0, stream>>>(
      qkv, qkv + D, vtg, ob, S, D3, D, H);
  gemm_bt2<0, 1, 0><<<dim3((T / 128) * (D / 256)), 512, 0, stream>>>(
      ob, wob, bo, h, h2, T, D, D);

  // MLP sub-block
  ln_fwd<<<dim3(T), 256, 0, stream>>>(h2, ln2_g, ln2_b, xb);
  gemm_bt2<1, 0, 1><<<dim3((T / 128) * (F / 256)), 512, 0, stream>>>(
      xb, wfcb, bfc, nullptr, ub, T, F, D);
  gemm_bt2<0, 1, 0><<<dim3((T / 128) * (D / 256)), 512, 0, stream>>>(
      ub, wprojb, bproj, h2, (float*)d_out, T, D, F);
}